// Round 2
// baseline (1305.761 us; speedup 1.0000x reference)
//
#include <hip/hip_runtime.h>

// Darcy flow graph PDE residual, atomic-based scatter-mean.
// R2 changes vs R1:
//  - unsafeAtomicAdd -> native global_atomic_add_f32 (no CAS loop, fire-and-forget)
//  - accumulators interleaved per node: acc1[n] = {sum0, cnt0, sum1, cnt1}
//  - 2 edges/thread, vectorized int2/float4 edge loads, uniform branches
//
// Workspace (floats): [acc1: 4N][acc2: 2N][tmp: 2N]; first 6N zeroed per launch.

#define BLK 256

__device__ __forceinline__ void fadd(float* p, float v) {
    unsafeAtomicAdd(p, v);   // global_atomic_add_f32, no return
}

__global__ __launch_bounds__(BLK) void edge_pass1(
    const int2* __restrict__ src2,       // [E/2]
    const int2* __restrict__ dst2,       // [E/2]
    const float4* __restrict__ attr2,    // [E/2] : {a0.x,a0.y,a1.x,a1.y}
    const float* __restrict__ x,         // [N]
    float* __restrict__ acc1,            // [4*N] : {sum0,cnt0,sum1,cnt1} per node
    int Epair)
{
    int t = blockIdx.x * BLK + threadIdx.x;
    if (t >= Epair) return;
    int2 s = src2[t];
    int2 d = dst2[t];
    float4 a = attr2[t];

    // edge e0 = 2t
    {
        float diff = x[s.x] - x[d.x];
        float* base = acc1 + ((size_t)d.x << 2);
        if (a.x != 0.0f) { fadd(base + 0, diff / a.x); fadd(base + 1, 1.0f); }
        if (a.y != 0.0f) { fadd(base + 2, diff / a.y); fadd(base + 3, 1.0f); }
    }
    // edge e1 = 2t+1
    {
        float diff = x[s.y] - x[d.y];
        float* base = acc1 + ((size_t)d.y << 2);
        if (a.z != 0.0f) { fadd(base + 0, diff / a.z); fadd(base + 1, 1.0f); }
        if (a.w != 0.0f) { fadd(base + 2, diff / a.w); fadd(base + 3, 1.0f); }
    }
}

__global__ __launch_bounds__(BLK) void node_pass1(
    const float4* __restrict__ acc1,     // {sum0,cnt0,sum1,cnt1}
    const float* __restrict__ a_x,
    float2* __restrict__ tmp,            // [N] : {tmp0, tmp1}
    int N)
{
    int i = blockIdx.x * BLK + threadIdx.x;
    if (i >= N) return;
    float4 v = acc1[i];
    float a = a_x[i];
    float2 t;
    t.x = a * (v.x / fmaxf(v.y, 1.0f));
    t.y = a * (v.z / fmaxf(v.w, 1.0f));
    tmp[i] = t;
}

__global__ __launch_bounds__(BLK) void edge_pass2(
    const int2* __restrict__ src2,
    const int2* __restrict__ dst2,
    const float4* __restrict__ attr2,
    const float* __restrict__ tmp,       // [2*N] : {tmp0,tmp1} interleaved
    float* __restrict__ acc2,            // [2*N] : {sum2,sum3} per node
    int Epair)
{
    int t = blockIdx.x * BLK + threadIdx.x;
    if (t >= Epair) return;
    int2 s = src2[t];
    int2 d = dst2[t];
    float4 a = attr2[t];

    {
        size_t sb = (size_t)s.x << 1, db = (size_t)d.x << 1;
        if (a.x != 0.0f) fadd(acc2 + db + 0, (tmp[sb + 0] - tmp[db + 0]) / a.x);
        if (a.y != 0.0f) fadd(acc2 + db + 1, (tmp[sb + 1] - tmp[db + 1]) / a.y);
    }
    {
        size_t sb = (size_t)s.y << 1, db = (size_t)d.y << 1;
        if (a.z != 0.0f) fadd(acc2 + db + 0, (tmp[sb + 0] - tmp[db + 0]) / a.z);
        if (a.w != 0.0f) fadd(acc2 + db + 1, (tmp[sb + 1] - tmp[db + 1]) / a.w);
    }
}

__global__ __launch_bounds__(BLK) void node_pass2(
    const float2* __restrict__ acc2,     // {sum2,sum3}
    const float4* __restrict__ acc1,     // for counts
    const int* __restrict__ mask,
    float* __restrict__ out,
    int N)
{
    int i = blockIdx.x * BLK + threadIdx.x;
    if (i >= N) return;
    float2 s = acc2[i];
    float4 c = acc1[i];
    float dxx = s.x / fmaxf(c.y, 1.0f);
    float dyy = s.y / fmaxf(c.w, 1.0f);
    float v = dxx + dyy + 1.0f;
    out[i] = v * (1.0f - (float)mask[i]);
}

extern "C" void kernel_launch(void* const* d_in, const int* in_sizes, int n_in,
                              void* d_out, int out_size, void* d_ws, size_t ws_size,
                              hipStream_t stream)
{
    const float* x    = (const float*)d_in[0];
    const float* a_x  = (const float*)d_in[1];
    const int*   eidx = (const int*)d_in[2];
    const float* attr = (const float*)d_in[3];
    const int*   mask = (const int*)d_in[4];
    float* out = (float*)d_out;

    const int N = in_sizes[0];
    const int E = in_sizes[2] / 2;
    const int Epair = E / 2;            // E is even (8M)

    float* ws   = (float*)d_ws;
    float* acc1 = ws;                    // 4N floats
    float* acc2 = ws + (size_t)4 * N;    // 2N floats
    float* tmp  = ws + (size_t)6 * N;    // 2N floats

    hipMemsetAsync(d_ws, 0, (size_t)6 * N * sizeof(float), stream);

    const int egrid = (Epair + BLK - 1) / BLK;
    const int ngrid = (N + BLK - 1) / BLK;

    edge_pass1<<<egrid, BLK, 0, stream>>>(
        (const int2*)eidx, (const int2*)(eidx + E), (const float4*)attr, x,
        acc1, Epair);
    node_pass1<<<ngrid, BLK, 0, stream>>>(
        (const float4*)acc1, a_x, (float2*)tmp, N);
    edge_pass2<<<egrid, BLK, 0, stream>>>(
        (const int2*)eidx, (const int2*)(eidx + E), (const float4*)attr,
        tmp, acc2, Epair);
    node_pass2<<<ngrid, BLK, 0, stream>>>(
        (const float2*)acc2, (const float4*)acc1, mask, out, N);
}

// Round 5
// 1042.620 us; speedup vs baseline: 1.2524x; 1.2524x over previous
//
#include <hip/hip_runtime.h>

// Darcy flow graph PDE residual — XCD-local atomic scatter.
//
// Mechanism: device-scope atomics execute at the fabric coherence point
// (~20 G atomics/s ceiling, measured R1/R2 -> 1.3 ms). Nodes are split into
// 8 slices; slice c is updated ONLY by blocks on physical XCD c (read via
// s_getreg HW_REG_XCC_ID, HW-verified m09), using WORKGROUP-scope atomics
// which stay in the local (per-XCD) L2. Every XCD scans all edges (the
// 128 MB edge stream is L3-resident) and filters by dst slice.
//
// Pass1 accumulator packs sum + 2^36*count into one f64 atomic.
// node_mid rewrites the same 16 B/node in place as {tmp0,tmp1,inv0,inv1},
// so pass2 needs only 2 gathers/edge and one f32 atomic.
//
// ws layout (bytes), total 20N+64 = ~20 MB (< proven 32 MB budget):
//   [0, 16N)      pk   : double2[N]  pass1 accum -> reused as float4[N]
//   [16N, 20N)    acc2 : float[N]
//   [20N, 20N+64) tickets : int[16]
// First 20N+64 bytes zeroed each launch (capture-safe hipMemsetAsync).

#define BLK   256
#define EPT   4
#define CHUNK (BLK * EPT)   // 1024 edges per chunk
#define GRAB  8             // chunks per ticket

// clang ext_vector types — required by __builtin_nontemporal_load
// (HIP_vector_type wrappers are rejected, R4 compile error).
typedef int   vi4 __attribute__((ext_vector_type(4)));
typedef float vf4 __attribute__((ext_vector_type(4)));

static constexpr double PK  = 68719476736.0;   // 2^36
static constexpr double PKI = 1.0 / 68719476736.0;

__device__ __forceinline__ int xcd_id() {
    // s_getreg(HW_REG_XCC_ID=20, offset 0, width 32) [measured m09: 0..7]
    return __builtin_amdgcn_s_getreg((31u << 11) | 20) & 7;
}

__device__ __forceinline__ void wg_add_d(double* p, double v) {
    __hip_atomic_fetch_add(p, v, __ATOMIC_RELAXED, __HIP_MEMORY_SCOPE_WORKGROUP);
}
__device__ __forceinline__ void wg_add_f(float* p, float v) {
    __hip_atomic_fetch_add(p, v, __ATOMIC_RELAXED, __HIP_MEMORY_SCOPE_WORKGROUP);
}

__global__ __launch_bounds__(BLK) void edge_pass1(
    const int* __restrict__ srcA, const int* __restrict__ dstA,
    const float* __restrict__ attr,         // [2*E] floats, 4 floats = 2 edges
    const float* __restrict__ x,
    double2* __restrict__ pk,
    int* __restrict__ tickets,
    int E, int nchunk, int sliceSz, int N)
{
    const int xcc = xcd_id();
    const int lo  = xcc * sliceSz;
    const int w   = min(sliceSz, N - lo);

    __shared__ int s_q;
    for (;;) {
        if (threadIdx.x == 0) s_q = atomicAdd(&tickets[xcc], 1);
        __syncthreads();
        const int q = s_q;
        __syncthreads();
        if (q * GRAB >= nchunk) break;

        for (int cc = 0; cc < GRAB; ++cc) {
            const int c = q * GRAB + cc;
            if (c >= nchunk) break;
            const int base = c * CHUNK + threadIdx.x * EPT;
            if (base >= E) continue;   // tail: E%4==0 so in-range => base+3 < E
            vi4 sv  = __builtin_nontemporal_load((const vi4*)&srcA[base]);
            vi4 dv  = __builtin_nontemporal_load((const vi4*)&dstA[base]);
            vf4 a01 = __builtin_nontemporal_load((const vf4*)&attr[2 * base]);
            vf4 a23 = __builtin_nontemporal_load((const vf4*)&attr[2 * base + 4]);

            #define P1(S, D, AX, AY)                                                  \
                if ((unsigned)((D) - lo) < (unsigned)w) {                             \
                    float diff = x[S] - x[D];                                         \
                    if ((AX) != 0.0f) wg_add_d(&pk[D].x, (double)(diff/(AX)) + PK);   \
                    if ((AY) != 0.0f) wg_add_d(&pk[D].y, (double)(diff/(AY)) + PK);   \
                }
            P1(sv.x, dv.x, a01.x, a01.y)
            P1(sv.y, dv.y, a01.z, a01.w)
            P1(sv.z, dv.z, a23.x, a23.y)
            P1(sv.w, dv.w, a23.z, a23.w)
            #undef P1
        }
    }
}

__global__ __launch_bounds__(BLK) void node_mid(
    double2* __restrict__ pk,            // in: packed sums; out (in place): float4
    const float* __restrict__ a_x,
    int N)
{
    float4* f4 = (float4*)pk;
    for (int i = blockIdx.x * BLK + threadIdx.x; i < N; i += gridDim.x * BLK) {
        double2 p = pk[i];
        double c0 = rint(p.x * PKI);
        double c1 = rint(p.y * PKI);
        float  s0 = (float)(p.x - c0 * PK);
        float  s1 = (float)(p.y - c1 * PK);
        float  i0 = 1.0f / (float)fmax(c0, 1.0);
        float  i1 = 1.0f / (float)fmax(c1, 1.0);
        float  a  = a_x[i];
        float4 t;
        t.x = a * s0 * i0;   // tmp0
        t.y = a * s1 * i1;   // tmp1
        t.z = i0;            // 1/max(cnt0,1)
        t.w = i1;            // 1/max(cnt1,1)
        f4[i] = t;
    }
}

__global__ __launch_bounds__(BLK) void edge_pass2(
    const int* __restrict__ srcA, const int* __restrict__ dstA,
    const float* __restrict__ attr,
    const float4* __restrict__ tf,       // {tmp0,tmp1,inv0,inv1} per node
    float* __restrict__ acc2,
    int* __restrict__ tickets,
    int E, int nchunk, int sliceSz, int N)
{
    const int xcc = xcd_id();
    const int lo  = xcc * sliceSz;
    const int w   = min(sliceSz, N - lo);

    __shared__ int s_q;
    for (;;) {
        if (threadIdx.x == 0) s_q = atomicAdd(&tickets[8 + xcc], 1);
        __syncthreads();
        const int q = s_q;
        __syncthreads();
        if (q * GRAB >= nchunk) break;

        for (int cc = 0; cc < GRAB; ++cc) {
            const int c = q * GRAB + cc;
            if (c >= nchunk) break;
            const int base = c * CHUNK + threadIdx.x * EPT;
            if (base >= E) continue;
            vi4 sv  = __builtin_nontemporal_load((const vi4*)&srcA[base]);
            vi4 dv  = __builtin_nontemporal_load((const vi4*)&dstA[base]);
            vf4 a01 = __builtin_nontemporal_load((const vf4*)&attr[2 * base]);
            vf4 a23 = __builtin_nontemporal_load((const vf4*)&attr[2 * base + 4]);

            #define P2(S, D, AX, AY)                                                  \
                if ((unsigned)((D) - lo) < (unsigned)w) {                             \
                    float4 ts = tf[S], td = tf[D];                                    \
                    float contrib = 0.0f; bool any = false;                           \
                    if ((AX) != 0.0f) { contrib += (ts.x - td.x) / (AX) * td.z; any = true; } \
                    if ((AY) != 0.0f) { contrib += (ts.y - td.y) / (AY) * td.w; any = true; } \
                    if (any) wg_add_f(&acc2[D], contrib);                             \
                }
            P2(sv.x, dv.x, a01.x, a01.y)
            P2(sv.y, dv.y, a01.z, a01.w)
            P2(sv.z, dv.z, a23.x, a23.y)
            P2(sv.w, dv.w, a23.z, a23.w)
            #undef P2
        }
    }
}

__global__ __launch_bounds__(BLK) void node_out(
    const float* __restrict__ acc2,
    const int* __restrict__ mask,
    float* __restrict__ out,
    int N)
{
    for (int i = blockIdx.x * BLK + threadIdx.x; i < N; i += gridDim.x * BLK) {
        out[i] = (acc2[i] + 1.0f) * (1.0f - (float)mask[i]);
    }
}

extern "C" void kernel_launch(void* const* d_in, const int* in_sizes, int n_in,
                              void* d_out, int out_size, void* d_ws, size_t ws_size,
                              hipStream_t stream)
{
    const float* x    = (const float*)d_in[0];
    const float* a_x  = (const float*)d_in[1];
    const int*   eidx = (const int*)d_in[2];
    const float* attr = (const float*)d_in[3];
    const int*   mask = (const int*)d_in[4];
    float* out = (float*)d_out;

    const int N = in_sizes[0];
    const int E = in_sizes[2] / 2;

    char* ws = (char*)d_ws;
    double2* pk      = (double2*)(ws);                      // 16N bytes
    float*   acc2    = (float*)(ws + (size_t)16 * N);       // 4N bytes
    int*     tickets = (int*)(ws + (size_t)20 * N);         // 64 bytes

    hipMemsetAsync(d_ws, 0, (size_t)20 * N + 64, stream);

    const int sliceSz = (N + 7) / 8;
    const int nchunk  = (E + CHUNK - 1) / CHUNK;
    const int EGRID   = 2048;
    int ngrid = (N + BLK - 1) / BLK;
    const int NGRID   = ngrid < 2048 ? ngrid : 2048;

    edge_pass1<<<EGRID, BLK, 0, stream>>>(
        eidx, eidx + E, attr, x, pk, tickets,
        E, nchunk, sliceSz, N);
    node_mid<<<NGRID, BLK, 0, stream>>>(pk, a_x, N);
    edge_pass2<<<EGRID, BLK, 0, stream>>>(
        eidx, eidx + E, attr, (const float4*)pk, acc2, tickets,
        E, nchunk, sliceSz, N);
    node_out<<<NGRID, BLK, 0, stream>>>(acc2, mask, out, N);
}

// Round 6
// 543.860 us; speedup vs baseline: 2.4009x; 1.9171x over previous
//
#include <hip/hip_runtime.h>

// Darcy flow graph PDE residual — bucket-binned LDS aggregation.
//
// Measured (R1/R2/R5): global f32/f64 atomics cap at ~17-20 G/s chip-wide
// regardless of scope (WRITE_SIZE = 32 B per atomic -> each is a fabric
// transaction). Atomic-per-edge designs floor at ~800 us. So: bin edges by
// dst bucket (4096 nodes) ONCE, then both scatter-mean passes stream each
// bucket's contiguous edges and accumulate in LDS (ds_add_f32), flushing
// densely. Zero global float atomics; ~370K int cursor atomics total.
//
// Edge record (8 B): w0 = src | (dst&4095)<<20 ; w1 = attr bits with LSB
// overwritten by comp (0=x,1=y). w1==0 => invalid edge (no valid component).
//
// Binned ws layout (needs E*8 + N*16 + 8KB ~= 80 MB):
//   [0, 8E)            ebuf  : int2[E]
//   [8E, 8E+16N)       tf    : float4[N] {tmp0,tmp1,inv0,inv1}
//   [8E+16N, +8KB)     counts[512] | offsets[520] | cursors[512]
// If ws_size is too small: fall back to the proven R5 atomic path (20N+64 B).

typedef int   vi2 __attribute__((ext_vector_type(2)));
typedef int   vi4 __attribute__((ext_vector_type(4)));
typedef float vf4 __attribute__((ext_vector_type(4)));

#define K_BSH  12
#define BUCKET (1 << K_BSH)        // 4096 nodes per bucket
#define KMAX   512

#define HB 512                     // hist blocks
#define HT 256
#define SB_T 512                   // scatter block threads
#define S_EPT 16
#define S_TILE (SB_T * S_EPT)      // 8192 edges per scatter block
#define PT 512                     // phase block threads

// ---------------- binned path ----------------

__global__ __launch_bounds__(HT) void k_hist(
    const int* __restrict__ dstA, int* __restrict__ counts, int E, int K)
{
    __shared__ int lh[KMAX];
    for (int i = threadIdx.x; i < K; i += HT) lh[i] = 0;
    __syncthreads();
    const int quads = E >> 2;                 // E % 4 == 0
    const int stride = HB * HT;
    for (int q = blockIdx.x * HT + threadIdx.x; q < quads; q += stride) {
        vi4 d = __builtin_nontemporal_load((const vi4*)&dstA[q << 2]);
        atomicAdd(&lh[d.x >> K_BSH], 1);
        atomicAdd(&lh[d.y >> K_BSH], 1);
        atomicAdd(&lh[d.z >> K_BSH], 1);
        atomicAdd(&lh[d.w >> K_BSH], 1);
    }
    __syncthreads();
    for (int i = threadIdx.x; i < K; i += HT)
        if (lh[i]) atomicAdd(&counts[i], lh[i]);
}

__global__ __launch_bounds__(KMAX) void k_scan(
    const int* __restrict__ counts, int* __restrict__ offsets,
    int* __restrict__ cursors, int K)
{
    __shared__ int s[KMAX];
    const int t = threadIdx.x;
    const int v = (t < K) ? counts[t] : 0;
    s[t] = v;
    __syncthreads();
    for (int d = 1; d < KMAX; d <<= 1) {
        int add = (t >= d) ? s[t - d] : 0;
        __syncthreads();
        s[t] += add;
        __syncthreads();
    }
    if (t < K) {
        int excl = s[t] - v;
        offsets[t] = excl;
        cursors[t] = excl;
        if (t == K - 1) offsets[K] = s[t];
    }
}

__global__ __launch_bounds__(SB_T) void k_scatter(
    const int* __restrict__ srcA, const int* __restrict__ dstA,
    const float* __restrict__ attr,
    int* __restrict__ cursors,
    int2* __restrict__ ebuf,
    int E, int K)
{
    __shared__ int lhist[KMAX], lbase[KMAX], lcnt[KMAX];
    for (int i = threadIdx.x; i < K; i += SB_T) { lhist[i] = 0; lcnt[i] = 0; }
    __syncthreads();

    const int base = blockIdx.x * S_TILE + threadIdx.x * S_EPT;
    int dv[S_EPT];

    // sweep A: dst -> block-local histogram
    #pragma unroll
    for (int j = 0; j < S_EPT; j += 4) {
        const int e = base + j;
        if (e < E) {                           // E%4==0 -> e+3 < E
            vi4 d = __builtin_nontemporal_load((const vi4*)&dstA[e]);
            dv[j+0] = d.x; dv[j+1] = d.y; dv[j+2] = d.z; dv[j+3] = d.w;
            atomicAdd(&lhist[d.x >> K_BSH], 1);
            atomicAdd(&lhist[d.y >> K_BSH], 1);
            atomicAdd(&lhist[d.z >> K_BSH], 1);
            atomicAdd(&lhist[d.w >> K_BSH], 1);
        } else {
            dv[j+0] = dv[j+1] = dv[j+2] = dv[j+3] = -1;
        }
    }
    __syncthreads();
    // reserve global ranges, one atomic per (block,bucket)
    for (int i = threadIdx.x; i < K; i += SB_T) {
        const int c = lhist[i];
        lbase[i] = c ? atomicAdd(&cursors[i], c) : 0;
    }
    __syncthreads();

    // sweep B: src+attr -> encode + place
    #pragma unroll
    for (int j = 0; j < S_EPT; j += 4) {
        const int e = base + j;
        if (e >= E) continue;
        vi4 s4 = __builtin_nontemporal_load((const vi4*)&srcA[e]);
        vf4 a0 = __builtin_nontemporal_load((const vf4*)&attr[2 * e]);
        vf4 a1 = __builtin_nontemporal_load((const vf4*)&attr[2 * e + 4]);

        #define PLACE(SRC, DST, AX, AY)                                        \
        {                                                                      \
            const int k    = (DST) >> K_BSH;                                   \
            const int r    = atomicAdd(&lcnt[k], 1);                           \
            const int slot = lbase[k] + r;                                     \
            const int comp = ((AX) != 0.0f) ? 0 : 1;                           \
            const float av = comp ? (AY) : (AX);                               \
            unsigned enc = 0u;                                                 \
            if ((AX) != 0.0f || (AY) != 0.0f)                                  \
                enc = (__float_as_uint(av) & ~1u) | (unsigned)comp;            \
            const int w0 = (SRC) | (((DST) & (BUCKET - 1)) << 20);             \
            ebuf[slot] = make_int2(w0, (int)enc);                              \
        }
        PLACE(s4.x, dv[j+0], a0.x, a0.y)
        PLACE(s4.y, dv[j+1], a0.z, a0.w)
        PLACE(s4.z, dv[j+2], a1.x, a1.y)
        PLACE(s4.w, dv[j+3], a1.z, a1.w)
        #undef PLACE
    }
}

__global__ __launch_bounds__(PT) void k_phase1(
    const int2* __restrict__ ebuf, const int* __restrict__ offsets,
    const float* __restrict__ x, const float* __restrict__ a_x,
    float4* __restrict__ tf, int N)
{
    __shared__ float s0[BUCKET], c0[BUCKET], s1[BUCKET], c1[BUCKET];
    const int k  = blockIdx.x;
    const int lo = k << K_BSH;
    for (int i = threadIdx.x; i < BUCKET; i += PT) {
        s0[i] = 0.0f; c0[i] = 0.0f; s1[i] = 0.0f; c1[i] = 0.0f;
    }
    __syncthreads();
    const int beg = offsets[k], end = offsets[k + 1];
    for (int i = beg + threadIdx.x; i < end; i += PT) {
        vi2 r = __builtin_nontemporal_load((const vi2*)ebuf + i);
        const unsigned enc = (unsigned)r.y;
        if (enc == 0u) continue;
        const int src  = r.x & 0xFFFFF;
        const int dlo  = ((unsigned)r.x) >> 20;
        const int comp = enc & 1;
        const float a  = __uint_as_float(enc);
        const float msg = (x[src] - x[lo + dlo]) / a;
        if (comp) { atomicAdd(&s1[dlo], msg); atomicAdd(&c1[dlo], 1.0f); }
        else      { atomicAdd(&s0[dlo], msg); atomicAdd(&c0[dlo], 1.0f); }
    }
    __syncthreads();
    for (int i = threadIdx.x; i < BUCKET; i += PT) {
        const int node = lo + i;
        if (node >= N) break;
        const float i0 = 1.0f / fmaxf(c0[i], 1.0f);
        const float i1 = 1.0f / fmaxf(c1[i], 1.0f);
        const float a  = a_x[node];
        tf[node] = make_float4(a * s0[i] * i0, a * s1[i] * i1, i0, i1);
    }
}

__global__ __launch_bounds__(PT) void k_phase2(
    const int2* __restrict__ ebuf, const int* __restrict__ offsets,
    const float4* __restrict__ tf, const int* __restrict__ mask,
    float* __restrict__ out, int N)
{
    __shared__ float acc[BUCKET];
    const int k  = blockIdx.x;
    const int lo = k << K_BSH;
    for (int i = threadIdx.x; i < BUCKET; i += PT) acc[i] = 0.0f;
    __syncthreads();
    const int beg = offsets[k], end = offsets[k + 1];
    for (int i = beg + threadIdx.x; i < end; i += PT) {
        vi2 r = __builtin_nontemporal_load((const vi2*)ebuf + i);
        const unsigned enc = (unsigned)r.y;
        if (enc == 0u) continue;
        const int src  = r.x & 0xFFFFF;
        const int dlo  = ((unsigned)r.x) >> 20;
        const int comp = enc & 1;
        const float a  = __uint_as_float(enc);
        const float4 ts = tf[src];
        const float4 td = tf[lo + dlo];
        const float tsv = comp ? ts.y : ts.x;
        const float tdv = comp ? td.y : td.x;
        const float ic  = comp ? td.w : td.z;
        atomicAdd(&acc[dlo], (tsv - tdv) / a * ic);
    }
    __syncthreads();
    for (int i = threadIdx.x; i < BUCKET; i += PT) {
        const int node = lo + i;
        if (node >= N) break;
        out[node] = (acc[i] + 1.0f) * (1.0f - (float)mask[node]);
    }
}

// ---------------- fallback path (proven R5, 1042 us) ----------------

#define BLK   256
#define EPT   4
#define CHUNK (BLK * EPT)
#define GRAB  8

static constexpr double PK  = 68719476736.0;   // 2^36
static constexpr double PKI = 1.0 / 68719476736.0;

__device__ __forceinline__ int xcd_id() {
    return __builtin_amdgcn_s_getreg((31u << 11) | 20) & 7;
}
__device__ __forceinline__ void wg_add_d(double* p, double v) {
    __hip_atomic_fetch_add(p, v, __ATOMIC_RELAXED, __HIP_MEMORY_SCOPE_WORKGROUP);
}
__device__ __forceinline__ void wg_add_f(float* p, float v) {
    __hip_atomic_fetch_add(p, v, __ATOMIC_RELAXED, __HIP_MEMORY_SCOPE_WORKGROUP);
}

__global__ __launch_bounds__(BLK) void edge_pass1(
    const int* __restrict__ srcA, const int* __restrict__ dstA,
    const float* __restrict__ attr, const float* __restrict__ x,
    double2* __restrict__ pk, int* __restrict__ tickets,
    int E, int nchunk, int sliceSz, int N)
{
    const int xcc = xcd_id();
    const int lo  = xcc * sliceSz;
    const int w   = min(sliceSz, N - lo);
    __shared__ int s_q;
    for (;;) {
        if (threadIdx.x == 0) s_q = atomicAdd(&tickets[xcc], 1);
        __syncthreads();
        const int q = s_q;
        __syncthreads();
        if (q * GRAB >= nchunk) break;
        for (int cc = 0; cc < GRAB; ++cc) {
            const int c = q * GRAB + cc;
            if (c >= nchunk) break;
            const int base = c * CHUNK + threadIdx.x * EPT;
            if (base >= E) continue;
            vi4 sv  = __builtin_nontemporal_load((const vi4*)&srcA[base]);
            vi4 dv  = __builtin_nontemporal_load((const vi4*)&dstA[base]);
            vf4 a01 = __builtin_nontemporal_load((const vf4*)&attr[2 * base]);
            vf4 a23 = __builtin_nontemporal_load((const vf4*)&attr[2 * base + 4]);
            #define P1(S, D, AX, AY)                                                  \
                if ((unsigned)((D) - lo) < (unsigned)w) {                             \
                    float diff = x[S] - x[D];                                         \
                    if ((AX) != 0.0f) wg_add_d(&pk[D].x, (double)(diff/(AX)) + PK);   \
                    if ((AY) != 0.0f) wg_add_d(&pk[D].y, (double)(diff/(AY)) + PK);   \
                }
            P1(sv.x, dv.x, a01.x, a01.y)
            P1(sv.y, dv.y, a01.z, a01.w)
            P1(sv.z, dv.z, a23.x, a23.y)
            P1(sv.w, dv.w, a23.z, a23.w)
            #undef P1
        }
    }
}

__global__ __launch_bounds__(BLK) void node_mid(
    double2* __restrict__ pk, const float* __restrict__ a_x, int N)
{
    float4* f4 = (float4*)pk;
    for (int i = blockIdx.x * BLK + threadIdx.x; i < N; i += gridDim.x * BLK) {
        double2 p = pk[i];
        double c0 = rint(p.x * PKI);
        double c1 = rint(p.y * PKI);
        float  s0 = (float)(p.x - c0 * PK);
        float  s1 = (float)(p.y - c1 * PK);
        float  i0 = 1.0f / (float)fmax(c0, 1.0);
        float  i1 = 1.0f / (float)fmax(c1, 1.0);
        float  a  = a_x[i];
        f4[i] = make_float4(a * s0 * i0, a * s1 * i1, i0, i1);
    }
}

__global__ __launch_bounds__(BLK) void edge_pass2(
    const int* __restrict__ srcA, const int* __restrict__ dstA,
    const float* __restrict__ attr, const float4* __restrict__ tf,
    float* __restrict__ acc2, int* __restrict__ tickets,
    int E, int nchunk, int sliceSz, int N)
{
    const int xcc = xcd_id();
    const int lo  = xcc * sliceSz;
    const int w   = min(sliceSz, N - lo);
    __shared__ int s_q;
    for (;;) {
        if (threadIdx.x == 0) s_q = atomicAdd(&tickets[8 + xcc], 1);
        __syncthreads();
        const int q = s_q;
        __syncthreads();
        if (q * GRAB >= nchunk) break;
        for (int cc = 0; cc < GRAB; ++cc) {
            const int c = q * GRAB + cc;
            if (c >= nchunk) break;
            const int base = c * CHUNK + threadIdx.x * EPT;
            if (base >= E) continue;
            vi4 sv  = __builtin_nontemporal_load((const vi4*)&srcA[base]);
            vi4 dv  = __builtin_nontemporal_load((const vi4*)&dstA[base]);
            vf4 a01 = __builtin_nontemporal_load((const vf4*)&attr[2 * base]);
            vf4 a23 = __builtin_nontemporal_load((const vf4*)&attr[2 * base + 4]);
            #define P2(S, D, AX, AY)                                                  \
                if ((unsigned)((D) - lo) < (unsigned)w) {                             \
                    float4 ts = tf[S], td = tf[D];                                    \
                    float contrib = 0.0f; bool any = false;                           \
                    if ((AX) != 0.0f) { contrib += (ts.x - td.x) / (AX) * td.z; any = true; } \
                    if ((AY) != 0.0f) { contrib += (ts.y - td.y) / (AY) * td.w; any = true; } \
                    if (any) wg_add_f(&acc2[D], contrib);                             \
                }
            P2(sv.x, dv.x, a01.x, a01.y)
            P2(sv.y, dv.y, a01.z, a01.w)
            P2(sv.z, dv.z, a23.x, a23.y)
            P2(sv.w, dv.w, a23.z, a23.w)
            #undef P2
        }
    }
}

__global__ __launch_bounds__(BLK) void node_out(
    const float* __restrict__ acc2, const int* __restrict__ mask,
    float* __restrict__ out, int N)
{
    for (int i = blockIdx.x * BLK + threadIdx.x; i < N; i += gridDim.x * BLK)
        out[i] = (acc2[i] + 1.0f) * (1.0f - (float)mask[i]);
}

// ---------------- launcher ----------------

extern "C" void kernel_launch(void* const* d_in, const int* in_sizes, int n_in,
                              void* d_out, int out_size, void* d_ws, size_t ws_size,
                              hipStream_t stream)
{
    const float* x    = (const float*)d_in[0];
    const float* a_x  = (const float*)d_in[1];
    const int*   eidx = (const int*)d_in[2];
    const float* attr = (const float*)d_in[3];
    const int*   mask = (const int*)d_in[4];
    float* out = (float*)d_out;

    const int N = in_sizes[0];
    const int E = in_sizes[2] / 2;
    const int K = (N + BUCKET - 1) >> K_BSH;

    const size_t need = (size_t)E * 8 + (size_t)N * 16 + 8192;

    if (ws_size >= need && N <= (1 << 20) && K <= KMAX) {
        char* p = (char*)d_ws;
        int2*   ebuf    = (int2*)p;
        float4* tf      = (float4*)(p + (size_t)E * 8);
        int*    counts  = (int*)(p + (size_t)E * 8 + (size_t)N * 16);
        int*    offsets = counts + KMAX;        // K+1 slots
        int*    cursors = counts + 2 * KMAX + 8;

        hipMemsetAsync(counts, 0, KMAX * sizeof(int), stream);

        const int* srcA = eidx;
        const int* dstA = eidx + E;
        const int SB = (E + S_TILE - 1) / S_TILE;

        k_hist<<<HB, HT, 0, stream>>>(dstA, counts, E, K);
        k_scan<<<1, KMAX, 0, stream>>>(counts, offsets, cursors, K);
        k_scatter<<<SB, SB_T, 0, stream>>>(srcA, dstA, attr, cursors, ebuf, E, K);
        k_phase1<<<K, PT, 0, stream>>>(ebuf, offsets, x, a_x, tf, N);
        k_phase2<<<K, PT, 0, stream>>>(ebuf, offsets, tf, mask, out, N);
    } else {
        // proven R5 fallback (20N+64 bytes of ws)
        char* ws = (char*)d_ws;
        double2* pk      = (double2*)(ws);
        float*   acc2    = (float*)(ws + (size_t)16 * N);
        int*     tickets = (int*)(ws + (size_t)20 * N);

        hipMemsetAsync(d_ws, 0, (size_t)20 * N + 64, stream);

        const int sliceSz = (N + 7) / 8;
        const int nchunk  = (E + CHUNK - 1) / CHUNK;
        const int EGRID   = 2048;
        int ngrid = (N + BLK - 1) / BLK;
        const int NGRID   = ngrid < 2048 ? ngrid : 2048;

        edge_pass1<<<EGRID, BLK, 0, stream>>>(
            eidx, eidx + E, attr, x, pk, tickets, E, nchunk, sliceSz, N);
        node_mid<<<NGRID, BLK, 0, stream>>>(pk, a_x, N);
        edge_pass2<<<EGRID, BLK, 0, stream>>>(
            eidx, eidx + E, attr, (const float4*)pk, acc2, tickets,
            E, nchunk, sliceSz, N);
        node_out<<<NGRID, BLK, 0, stream>>>(acc2, mask, out, N);
    }
}

// Round 7
// 516.735 us; speedup vs baseline: 2.5269x; 1.0525x over previous
//
#include <hip/hip_runtime.h>

// Darcy flow graph PDE residual — bucket-binned LDS aggregation, rev 2.
//
// Measured: global float atomics ~17-20 G/s chip-wide (R1/R2/R5) -> bin edges
// by dst bucket once, aggregate in LDS. R6 measured k_phase2 at 161 us,
// occupancy 20% (K=245 blocks only), FETCH 555 MB (random 16B tf gathers).
// Rev 2: BUCKET 1024 (K~977 blocks -> ~30 waves/CU), tf split into tmp2
// (float2, gathered by src, 8 MB) + inv2 (dst-only), bucket-local values
// preloaded into LDS so phase2 does ONE 8B gather per edge.
//
// Edge record (8 B): w0 = src | dlo<<20 (dlo 10 bits); w1 = attr bits with
// LSB overwritten by comp (0=x,1=y); w1==0 => invalid edge.
//
// Binned ws layout (needs 8E + 16N + 16KB ~= 80 MB, proven to fit in R6):
//   [0, 8E)             ebuf : int2[E]
//   [8E, 8E+8N)         tmp2 : float2[N]
//   [8E+8N, 8E+16N)     inv2 : float2[N]
//   [8E+16N, +16KB)     counts[1024] | offsets[1025] | cursors[1024]
// Fallback (ws too small): proven R5 atomic path (1042 us).

typedef int   vi2 __attribute__((ext_vector_type(2)));
typedef int   vi4 __attribute__((ext_vector_type(4)));
typedef float vf4 __attribute__((ext_vector_type(4)));

#define K_BSH  10
#define BUCKET (1 << K_BSH)        // 1024 nodes per bucket
#define KMAX   1024

#define HB 256                     // hist grid
#define HT 256
#define SB_T 512                   // scatter block threads
#define S_EPT 32
#define S_TILE (SB_T * S_EPT)      // 16384 edges per scatter block
#define PT 512                     // phase block threads

// ---------------- binned path ----------------

__global__ __launch_bounds__(HT) void k_hist(
    const int* __restrict__ dstA, int* __restrict__ counts, int E, int K)
{
    __shared__ int lh[KMAX];
    for (int i = threadIdx.x; i < K; i += HT) lh[i] = 0;
    __syncthreads();
    const int quads = E >> 2;                 // E % 4 == 0
    const int stride = HB * HT;
    for (int q = blockIdx.x * HT + threadIdx.x; q < quads; q += stride) {
        vi4 d = __builtin_nontemporal_load((const vi4*)&dstA[q << 2]);
        atomicAdd(&lh[d.x >> K_BSH], 1);
        atomicAdd(&lh[d.y >> K_BSH], 1);
        atomicAdd(&lh[d.z >> K_BSH], 1);
        atomicAdd(&lh[d.w >> K_BSH], 1);
    }
    __syncthreads();
    for (int i = threadIdx.x; i < K; i += HT)
        if (lh[i]) atomicAdd(&counts[i], lh[i]);
}

__global__ __launch_bounds__(KMAX) void k_scan(
    const int* __restrict__ counts, int* __restrict__ offsets,
    int* __restrict__ cursors, int K)
{
    __shared__ int s[KMAX];
    const int t = threadIdx.x;
    const int v = (t < K) ? counts[t] : 0;
    s[t] = v;
    __syncthreads();
    for (int d = 1; d < KMAX; d <<= 1) {
        int add = (t >= d) ? s[t - d] : 0;
        __syncthreads();
        s[t] += add;
        __syncthreads();
    }
    if (t < K) {
        int excl = s[t] - v;
        offsets[t] = excl;
        cursors[t] = excl;
        if (t == K - 1) offsets[K] = s[t];
    }
}

__global__ __launch_bounds__(SB_T) void k_scatter(
    const int* __restrict__ srcA, const int* __restrict__ dstA,
    const float* __restrict__ attr,
    int* __restrict__ cursors,
    int2* __restrict__ ebuf,
    int E, int K)
{
    __shared__ int lhist[KMAX], lbase[KMAX], lcnt[KMAX];
    for (int i = threadIdx.x; i < K; i += SB_T) { lhist[i] = 0; lcnt[i] = 0; }
    __syncthreads();

    const int base = blockIdx.x * S_TILE + threadIdx.x * S_EPT;
    int dv[S_EPT];

    // sweep A: dst -> block-local histogram
    #pragma unroll
    for (int j = 0; j < S_EPT; j += 4) {
        const int e = base + j;
        if (e < E) {                           // E%4==0 -> e+3 < E
            vi4 d = __builtin_nontemporal_load((const vi4*)&dstA[e]);
            dv[j+0] = d.x; dv[j+1] = d.y; dv[j+2] = d.z; dv[j+3] = d.w;
            atomicAdd(&lhist[d.x >> K_BSH], 1);
            atomicAdd(&lhist[d.y >> K_BSH], 1);
            atomicAdd(&lhist[d.z >> K_BSH], 1);
            atomicAdd(&lhist[d.w >> K_BSH], 1);
        } else {
            dv[j+0] = dv[j+1] = dv[j+2] = dv[j+3] = -1;
        }
    }
    __syncthreads();
    // reserve global slot ranges, one atomic per (block,bucket)
    for (int i = threadIdx.x; i < K; i += SB_T) {
        const int c = lhist[i];
        lbase[i] = c ? atomicAdd(&cursors[i], c) : 0;
    }
    __syncthreads();

    // sweep B: src+attr -> encode + place
    #pragma unroll
    for (int j = 0; j < S_EPT; j += 4) {
        const int e = base + j;
        if (e >= E) continue;
        vi4 s4 = __builtin_nontemporal_load((const vi4*)&srcA[e]);
        vf4 a0 = __builtin_nontemporal_load((const vf4*)&attr[2 * e]);
        vf4 a1 = __builtin_nontemporal_load((const vf4*)&attr[2 * e + 4]);

        #define PLACE(SRC, DST, AX, AY)                                        \
        {                                                                      \
            const int k    = (DST) >> K_BSH;                                   \
            const int r    = atomicAdd(&lcnt[k], 1);                           \
            const int slot = lbase[k] + r;                                     \
            const int comp = ((AX) != 0.0f) ? 0 : 1;                           \
            const float av = comp ? (AY) : (AX);                               \
            unsigned enc = 0u;                                                 \
            if ((AX) != 0.0f || (AY) != 0.0f)                                  \
                enc = (__float_as_uint(av) & ~1u) | (unsigned)comp;            \
            const int w0 = (SRC) | (((DST) & (BUCKET - 1)) << 20);             \
            ebuf[slot] = make_int2(w0, (int)enc);                              \
        }
        PLACE(s4.x, dv[j+0], a0.x, a0.y)
        PLACE(s4.y, dv[j+1], a0.z, a0.w)
        PLACE(s4.z, dv[j+2], a1.x, a1.y)
        PLACE(s4.w, dv[j+3], a1.z, a1.w)
        #undef PLACE
    }
}

__global__ __launch_bounds__(PT) void k_phase1(
    const int2* __restrict__ ebuf, const int* __restrict__ offsets,
    const float* __restrict__ x, const float* __restrict__ a_x,
    float2* __restrict__ tmp2, float2* __restrict__ inv2, int N)
{
    __shared__ float s0[BUCKET], c0[BUCKET], s1[BUCKET], c1[BUCKET];
    __shared__ float xl[BUCKET];
    const int k  = blockIdx.x;
    const int lo = k << K_BSH;
    for (int i = threadIdx.x; i < BUCKET; i += PT) {
        s0[i] = 0.0f; c0[i] = 0.0f; s1[i] = 0.0f; c1[i] = 0.0f;
        const int node = lo + i;
        xl[i] = (node < N) ? x[node] : 0.0f;
    }
    __syncthreads();
    const int beg = offsets[k], end = offsets[k + 1];
    for (int i = beg + threadIdx.x; i < end; i += PT) {
        vi2 r = __builtin_nontemporal_load((const vi2*)ebuf + i);
        const unsigned enc = (unsigned)r.y;
        if (enc == 0u) continue;
        const int src  = r.x & 0xFFFFF;
        const int dlo  = ((unsigned)r.x) >> 20;
        const int comp = enc & 1;
        const float a  = __uint_as_float(enc);
        const float msg = (x[src] - xl[dlo]) / a;
        if (comp) { atomicAdd(&s1[dlo], msg); atomicAdd(&c1[dlo], 1.0f); }
        else      { atomicAdd(&s0[dlo], msg); atomicAdd(&c0[dlo], 1.0f); }
    }
    __syncthreads();
    for (int i = threadIdx.x; i < BUCKET; i += PT) {
        const int node = lo + i;
        if (node >= N) break;
        const float i0 = 1.0f / fmaxf(c0[i], 1.0f);
        const float i1 = 1.0f / fmaxf(c1[i], 1.0f);
        const float a  = a_x[node];
        float2 t; t.x = a * s0[i] * i0; t.y = a * s1[i] * i1;
        float2 v; v.x = i0; v.y = i1;
        tmp2[node] = t;
        inv2[node] = v;
    }
}

__global__ __launch_bounds__(PT) void k_phase2(
    const int2* __restrict__ ebuf, const int* __restrict__ offsets,
    const float2* __restrict__ tmp2, const float2* __restrict__ inv2,
    const int* __restrict__ mask,
    float* __restrict__ out, int N)
{
    __shared__ float acc[BUCKET];
    __shared__ float2 tl[BUCKET], il[BUCKET];
    const int k  = blockIdx.x;
    const int lo = k << K_BSH;
    for (int i = threadIdx.x; i < BUCKET; i += PT) {
        acc[i] = 0.0f;
        const int node = lo + i;
        if (node < N) { tl[i] = tmp2[node]; il[i] = inv2[node]; }
        else          { tl[i] = make_float2(0.f, 0.f); il[i] = make_float2(0.f, 0.f); }
    }
    __syncthreads();
    const int beg = offsets[k], end = offsets[k + 1];
    for (int i = beg + threadIdx.x; i < end; i += PT) {
        vi2 r = __builtin_nontemporal_load((const vi2*)ebuf + i);
        const unsigned enc = (unsigned)r.y;
        if (enc == 0u) continue;
        const int src  = r.x & 0xFFFFF;
        const int dlo  = ((unsigned)r.x) >> 20;
        const int comp = enc & 1;
        const float a  = __uint_as_float(enc);
        const float2 ts = tmp2[src];          // the ONLY global gather
        const float2 td = tl[dlo];
        const float2 ic = il[dlo];
        const float tsv = comp ? ts.y : ts.x;
        const float tdv = comp ? td.y : td.x;
        const float icv = comp ? ic.y : ic.x;
        atomicAdd(&acc[dlo], (tsv - tdv) / a * icv);
    }
    __syncthreads();
    for (int i = threadIdx.x; i < BUCKET; i += PT) {
        const int node = lo + i;
        if (node >= N) break;
        out[node] = (acc[i] + 1.0f) * (1.0f - (float)mask[node]);
    }
}

// ---------------- fallback path (proven R5, 1042 us) ----------------

#define BLK   256
#define EPT   4
#define CHUNK (BLK * EPT)
#define GRAB  8

static constexpr double PK  = 68719476736.0;   // 2^36
static constexpr double PKI = 1.0 / 68719476736.0;

__device__ __forceinline__ int xcd_id() {
    return __builtin_amdgcn_s_getreg((31u << 11) | 20) & 7;
}
__device__ __forceinline__ void wg_add_d(double* p, double v) {
    __hip_atomic_fetch_add(p, v, __ATOMIC_RELAXED, __HIP_MEMORY_SCOPE_WORKGROUP);
}
__device__ __forceinline__ void wg_add_f(float* p, float v) {
    __hip_atomic_fetch_add(p, v, __ATOMIC_RELAXED, __HIP_MEMORY_SCOPE_WORKGROUP);
}

__global__ __launch_bounds__(BLK) void edge_pass1(
    const int* __restrict__ srcA, const int* __restrict__ dstA,
    const float* __restrict__ attr, const float* __restrict__ x,
    double2* __restrict__ pk, int* __restrict__ tickets,
    int E, int nchunk, int sliceSz, int N)
{
    const int xcc = xcd_id();
    const int lo  = xcc * sliceSz;
    const int w   = min(sliceSz, N - lo);
    __shared__ int s_q;
    for (;;) {
        if (threadIdx.x == 0) s_q = atomicAdd(&tickets[xcc], 1);
        __syncthreads();
        const int q = s_q;
        __syncthreads();
        if (q * GRAB >= nchunk) break;
        for (int cc = 0; cc < GRAB; ++cc) {
            const int c = q * GRAB + cc;
            if (c >= nchunk) break;
            const int base = c * CHUNK + threadIdx.x * EPT;
            if (base >= E) continue;
            vi4 sv  = __builtin_nontemporal_load((const vi4*)&srcA[base]);
            vi4 dv  = __builtin_nontemporal_load((const vi4*)&dstA[base]);
            vf4 a01 = __builtin_nontemporal_load((const vf4*)&attr[2 * base]);
            vf4 a23 = __builtin_nontemporal_load((const vf4*)&attr[2 * base + 4]);
            #define P1(S, D, AX, AY)                                                  \
                if ((unsigned)((D) - lo) < (unsigned)w) {                             \
                    float diff = x[S] - x[D];                                         \
                    if ((AX) != 0.0f) wg_add_d(&pk[D].x, (double)(diff/(AX)) + PK);   \
                    if ((AY) != 0.0f) wg_add_d(&pk[D].y, (double)(diff/(AY)) + PK);   \
                }
            P1(sv.x, dv.x, a01.x, a01.y)
            P1(sv.y, dv.y, a01.z, a01.w)
            P1(sv.z, dv.z, a23.x, a23.y)
            P1(sv.w, dv.w, a23.z, a23.w)
            #undef P1
        }
    }
}

__global__ __launch_bounds__(BLK) void node_mid(
    double2* __restrict__ pk, const float* __restrict__ a_x, int N)
{
    float4* f4 = (float4*)pk;
    for (int i = blockIdx.x * BLK + threadIdx.x; i < N; i += gridDim.x * BLK) {
        double2 p = pk[i];
        double c0 = rint(p.x * PKI);
        double c1 = rint(p.y * PKI);
        float  s0 = (float)(p.x - c0 * PK);
        float  s1 = (float)(p.y - c1 * PK);
        float  i0 = 1.0f / (float)fmax(c0, 1.0);
        float  i1 = 1.0f / (float)fmax(c1, 1.0);
        float  a  = a_x[i];
        f4[i] = make_float4(a * s0 * i0, a * s1 * i1, i0, i1);
    }
}

__global__ __launch_bounds__(BLK) void edge_pass2(
    const int* __restrict__ srcA, const int* __restrict__ dstA,
    const float* __restrict__ attr, const float4* __restrict__ tf,
    float* __restrict__ acc2, int* __restrict__ tickets,
    int E, int nchunk, int sliceSz, int N)
{
    const int xcc = xcd_id();
    const int lo  = xcc * sliceSz;
    const int w   = min(sliceSz, N - lo);
    __shared__ int s_q;
    for (;;) {
        if (threadIdx.x == 0) s_q = atomicAdd(&tickets[8 + xcc], 1);
        __syncthreads();
        const int q = s_q;
        __syncthreads();
        if (q * GRAB >= nchunk) break;
        for (int cc = 0; cc < GRAB; ++cc) {
            const int c = q * GRAB + cc;
            if (c >= nchunk) break;
            const int base = c * CHUNK + threadIdx.x * EPT;
            if (base >= E) continue;
            vi4 sv  = __builtin_nontemporal_load((const vi4*)&srcA[base]);
            vi4 dv  = __builtin_nontemporal_load((const vi4*)&dstA[base]);
            vf4 a01 = __builtin_nontemporal_load((const vf4*)&attr[2 * base]);
            vf4 a23 = __builtin_nontemporal_load((const vf4*)&attr[2 * base + 4]);
            #define P2(S, D, AX, AY)                                                  \
                if ((unsigned)((D) - lo) < (unsigned)w) {                             \
                    float4 ts = tf[S], td = tf[D];                                    \
                    float contrib = 0.0f; bool any = false;                           \
                    if ((AX) != 0.0f) { contrib += (ts.x - td.x) / (AX) * td.z; any = true; } \
                    if ((AY) != 0.0f) { contrib += (ts.y - td.y) / (AY) * td.w; any = true; } \
                    if (any) wg_add_f(&acc2[D], contrib);                             \
                }
            P2(sv.x, dv.x, a01.x, a01.y)
            P2(sv.y, dv.y, a01.z, a01.w)
            P2(sv.z, dv.z, a23.x, a23.y)
            P2(sv.w, dv.w, a23.z, a23.w)
            #undef P2
        }
    }
}

__global__ __launch_bounds__(BLK) void node_out(
    const float* __restrict__ acc2, const int* __restrict__ mask,
    float* __restrict__ out, int N)
{
    for (int i = blockIdx.x * BLK + threadIdx.x; i < N; i += gridDim.x * BLK)
        out[i] = (acc2[i] + 1.0f) * (1.0f - (float)mask[i]);
}

// ---------------- launcher ----------------

extern "C" void kernel_launch(void* const* d_in, const int* in_sizes, int n_in,
                              void* d_out, int out_size, void* d_ws, size_t ws_size,
                              hipStream_t stream)
{
    const float* x    = (const float*)d_in[0];
    const float* a_x  = (const float*)d_in[1];
    const int*   eidx = (const int*)d_in[2];
    const float* attr = (const float*)d_in[3];
    const int*   mask = (const int*)d_in[4];
    float* out = (float*)d_out;

    const int N = in_sizes[0];
    const int E = in_sizes[2] / 2;
    const int K = (N + BUCKET - 1) >> K_BSH;

    const size_t need = (size_t)E * 8 + (size_t)N * 16 + 16384;

    if (ws_size >= need && N <= (1 << 20) && K <= KMAX) {
        char* p = (char*)d_ws;
        int2*   ebuf    = (int2*)p;
        float2* tmp2    = (float2*)(p + (size_t)E * 8);
        float2* inv2    = (float2*)(p + (size_t)E * 8 + (size_t)N * 8);
        int*    counts  = (int*)(p + (size_t)E * 8 + (size_t)N * 16);
        int*    offsets = counts + KMAX;          // K+1 slots
        int*    cursors = counts + 2 * KMAX + 8;

        hipMemsetAsync(counts, 0, KMAX * sizeof(int), stream);

        const int* srcA = eidx;
        const int* dstA = eidx + E;
        const int SB = (E + S_TILE - 1) / S_TILE;

        k_hist<<<HB, HT, 0, stream>>>(dstA, counts, E, K);
        k_scan<<<1, KMAX, 0, stream>>>(counts, offsets, cursors, K);
        k_scatter<<<SB, SB_T, 0, stream>>>(srcA, dstA, attr, cursors, ebuf, E, K);
        k_phase1<<<K, PT, 0, stream>>>(ebuf, offsets, x, a_x, tmp2, inv2, N);
        k_phase2<<<K, PT, 0, stream>>>(ebuf, offsets, tmp2, inv2, mask, out, N);
    } else {
        // proven R5 fallback (20N+64 bytes of ws)
        char* ws = (char*)d_ws;
        double2* pk      = (double2*)(ws);
        float*   acc2    = (float*)(ws + (size_t)16 * N);
        int*     tickets = (int*)(ws + (size_t)20 * N);

        hipMemsetAsync(d_ws, 0, (size_t)20 * N + 64, stream);

        const int sliceSz = (N + 7) / 8;
        const int nchunk  = (E + CHUNK - 1) / CHUNK;
        const int EGRID   = 2048;
        int ngrid = (N + BLK - 1) / BLK;
        const int NGRID   = ngrid < 2048 ? ngrid : 2048;

        edge_pass1<<<EGRID, BLK, 0, stream>>>(
            eidx, eidx + E, attr, x, pk, tickets, E, nchunk, sliceSz, N);
        node_mid<<<NGRID, BLK, 0, stream>>>(pk, a_x, N);
        edge_pass2<<<EGRID, BLK, 0, stream>>>(
            eidx, eidx + E, attr, (const float4*)pk, acc2, tickets,
            E, nchunk, sliceSz, N);
        node_out<<<NGRID, BLK, 0, stream>>>(acc2, mask, out, N);
    }
}

// Round 8
// 421.984 us; speedup vs baseline: 3.0943x; 1.2245x over previous
//
#include <hip/hip_runtime.h>

// Darcy flow graph PDE residual — bucket-binned LDS aggregation, rev 3.
//
// Measured: global float atomics ~17-20 G/s chip-wide (R1/R2/R5) -> bin edges
// by dst bucket once, aggregate in LDS. R7: k_scatter 187 us dominated by a
// per-thread dv[32] array spilled to scratch (VGPR_Count=32 proves it).
// Rev 3: scatter = two streaming sweeps over a contiguous span (no register
// staging, dst read twice); phase1 packs sum+2^36*cnt into ONE LDS f64 atomic
// (ds_add_f64); phases read 2 records/thread (vi4).
//
// Edge record (8 B): w0 = src | dlo<<20 (dlo 10 bits); w1 = attr bits with
// LSB overwritten by comp (0=x,1=y); w1==0 => invalid edge.
//
// Binned ws layout (needs 8E + 16N + 16KB ~= 80 MB, proven to fit in R6/R7):
//   [0, 8E)             ebuf : int2[E]
//   [8E, 8E+8N)         tmp2 : float2[N]
//   [8E+8N, 8E+16N)     inv2 : float2[N]
//   [8E+16N, +16KB)     counts[1024] | offsets[1025] | cursors[1024]
// Fallback (ws too small): proven R5 atomic path (1042 us).

typedef int   vi2 __attribute__((ext_vector_type(2)));
typedef int   vi4 __attribute__((ext_vector_type(4)));
typedef float vf4 __attribute__((ext_vector_type(4)));

#define K_BSH  10
#define BUCKET (1 << K_BSH)        // 1024 nodes per bucket
#define KMAX   1024

#define HB 512                     // hist grid
#define HT 256
#define SB   512                   // scatter blocks
#define SB_T 512                   // scatter threads
#define PT 512                     // phase block threads

static constexpr double PK  = 68719476736.0;   // 2^36
static constexpr double PKI = 1.0 / 68719476736.0;

// ---------------- binned path ----------------

__global__ __launch_bounds__(HT) void k_hist(
    const int* __restrict__ dstA, int* __restrict__ counts, int E, int K)
{
    __shared__ int lh[KMAX];
    for (int i = threadIdx.x; i < K; i += HT) lh[i] = 0;
    __syncthreads();
    const int quads = E >> 2;                 // E % 4 == 0
    const int stride = HB * HT;
    for (int q = blockIdx.x * HT + threadIdx.x; q < quads; q += stride) {
        vi4 d = __builtin_nontemporal_load((const vi4*)&dstA[q << 2]);
        atomicAdd(&lh[d.x >> K_BSH], 1);
        atomicAdd(&lh[d.y >> K_BSH], 1);
        atomicAdd(&lh[d.z >> K_BSH], 1);
        atomicAdd(&lh[d.w >> K_BSH], 1);
    }
    __syncthreads();
    for (int i = threadIdx.x; i < K; i += HT)
        if (lh[i]) atomicAdd(&counts[i], lh[i]);
}

__global__ __launch_bounds__(KMAX) void k_scan(
    const int* __restrict__ counts, int* __restrict__ offsets,
    int* __restrict__ cursors, int K)
{
    __shared__ int s[KMAX];
    const int t = threadIdx.x;
    const int v = (t < K) ? counts[t] : 0;
    s[t] = v;
    __syncthreads();
    for (int d = 1; d < KMAX; d <<= 1) {
        int add = (t >= d) ? s[t - d] : 0;
        __syncthreads();
        s[t] += add;
        __syncthreads();
    }
    if (t < K) {
        int excl = s[t] - v;
        offsets[t] = excl;
        cursors[t] = excl;
        if (t == K - 1) offsets[K] = s[t];
    }
}

__global__ __launch_bounds__(SB_T) void k_scatter(
    const int* __restrict__ srcA, const int* __restrict__ dstA,
    const float* __restrict__ attr,
    int* __restrict__ cursors,
    int2* __restrict__ ebuf,
    int E, int K, int span)
{
    __shared__ int lhist[KMAX], lbase[KMAX], lcnt[KMAX];
    for (int i = threadIdx.x; i < K; i += SB_T) { lhist[i] = 0; lcnt[i] = 0; }
    __syncthreads();

    const int beg = blockIdx.x * span;           // span % 4 == 0
    const int end = min(beg + span, E);          // E % 4 == 0

    // sweep A: dst -> block-local histogram (plain loads: keep in L2 for B)
    for (int e = beg + (int)threadIdx.x * 4; e < end; e += SB_T * 4) {
        vi4 d = *(const vi4*)&dstA[e];
        atomicAdd(&lhist[d.x >> K_BSH], 1);
        atomicAdd(&lhist[d.y >> K_BSH], 1);
        atomicAdd(&lhist[d.z >> K_BSH], 1);
        atomicAdd(&lhist[d.w >> K_BSH], 1);
    }
    __syncthreads();
    // reserve global slot ranges, one atomic per (block,bucket)
    for (int i = threadIdx.x; i < K; i += SB_T) {
        const int c = lhist[i];
        lbase[i] = c ? atomicAdd(&cursors[i], c) : 0;
    }
    __syncthreads();

    // sweep B: re-read streams, encode + place
    for (int e = beg + (int)threadIdx.x * 4; e < end; e += SB_T * 4) {
        vi4 s4 = __builtin_nontemporal_load((const vi4*)&srcA[e]);
        vi4 d4 = __builtin_nontemporal_load((const vi4*)&dstA[e]);
        vf4 a0 = __builtin_nontemporal_load((const vf4*)&attr[2 * e]);
        vf4 a1 = __builtin_nontemporal_load((const vf4*)&attr[2 * e + 4]);

        #define PLACE(SRC, DST, AX, AY)                                        \
        {                                                                      \
            const int k    = (DST) >> K_BSH;                                   \
            const int r    = atomicAdd(&lcnt[k], 1);                           \
            const int slot = lbase[k] + r;                                     \
            const int comp = ((AX) != 0.0f) ? 0 : 1;                           \
            const float av = comp ? (AY) : (AX);                               \
            unsigned enc = 0u;                                                 \
            if ((AX) != 0.0f || (AY) != 0.0f)                                  \
                enc = (__float_as_uint(av) & ~1u) | (unsigned)comp;            \
            const int w0 = (SRC) | (((DST) & (BUCKET - 1)) << 20);             \
            ebuf[slot] = make_int2(w0, (int)enc);                              \
        }
        PLACE(s4.x, d4.x, a0.x, a0.y)
        PLACE(s4.y, d4.y, a0.z, a0.w)
        PLACE(s4.z, d4.z, a1.x, a1.y)
        PLACE(s4.w, d4.w, a1.z, a1.w)
        #undef PLACE
    }
}

__global__ __launch_bounds__(PT) void k_phase1(
    const int2* __restrict__ ebuf, const int* __restrict__ offsets,
    const float* __restrict__ x, const float* __restrict__ a_x,
    float2* __restrict__ tmp2, float2* __restrict__ inv2, int N)
{
    __shared__ double pk0[BUCKET], pk1[BUCKET];   // sum + 2^36*cnt packed
    __shared__ float xl[BUCKET];
    const int k  = blockIdx.x;
    const int lo = k << K_BSH;
    for (int i = threadIdx.x; i < BUCKET; i += PT) {
        pk0[i] = 0.0; pk1[i] = 0.0;
        const int node = lo + i;
        xl[i] = (node < N) ? x[node] : 0.0f;
    }
    __syncthreads();
    const int beg = offsets[k], end = offsets[k + 1];
    const int start = beg & ~1;                   // 16B-aligned vi4 loads

    #define P1REC(W0, W1)                                                      \
    {                                                                          \
        const unsigned enc = (unsigned)(W1);                                   \
        if (enc != 0u) {                                                       \
            const int src  = (W0) & 0xFFFFF;                                   \
            const int dlo  = ((unsigned)(W0)) >> 20;                           \
            const float a  = __uint_as_float(enc);                             \
            const float msg = (x[src] - xl[dlo]) / a;                          \
            double* p = (enc & 1) ? pk1 : pk0;                                 \
            atomicAdd(&p[dlo], (double)msg + PK);                              \
        }                                                                      \
    }
    for (int i = start + (int)threadIdx.x * 2; i < end; i += PT * 2) {
        vi4 rr = __builtin_nontemporal_load((const vi4*)(ebuf + i));
        if (i >= beg)    P1REC(rr.x, rr.y)
        if (i + 1 < end) P1REC(rr.z, rr.w)
    }
    #undef P1REC

    __syncthreads();
    for (int i = threadIdx.x; i < BUCKET; i += PT) {
        const int node = lo + i;
        if (node >= N) break;
        const double p0 = pk0[i], p1 = pk1[i];
        const double c0 = rint(p0 * PKI);
        const double c1 = rint(p1 * PKI);
        const float  s0 = (float)(p0 - c0 * PK);
        const float  s1 = (float)(p1 - c1 * PK);
        const float  i0 = 1.0f / (float)fmax(c0, 1.0);
        const float  i1 = 1.0f / (float)fmax(c1, 1.0);
        const float  a  = a_x[node];
        float2 t; t.x = a * s0 * i0; t.y = a * s1 * i1;
        float2 v; v.x = i0; v.y = i1;
        tmp2[node] = t;
        inv2[node] = v;
    }
}

__global__ __launch_bounds__(PT) void k_phase2(
    const int2* __restrict__ ebuf, const int* __restrict__ offsets,
    const float2* __restrict__ tmp2, const float2* __restrict__ inv2,
    const int* __restrict__ mask,
    float* __restrict__ out, int N)
{
    __shared__ float acc[BUCKET];
    __shared__ float2 tl[BUCKET], il[BUCKET];
    const int k  = blockIdx.x;
    const int lo = k << K_BSH;
    for (int i = threadIdx.x; i < BUCKET; i += PT) {
        acc[i] = 0.0f;
        const int node = lo + i;
        if (node < N) { tl[i] = tmp2[node]; il[i] = inv2[node]; }
        else          { tl[i] = make_float2(0.f, 0.f); il[i] = make_float2(0.f, 0.f); }
    }
    __syncthreads();
    const int beg = offsets[k], end = offsets[k + 1];
    const int start = beg & ~1;

    #define P2REC(W0, W1)                                                      \
    {                                                                          \
        const unsigned enc = (unsigned)(W1);                                   \
        if (enc != 0u) {                                                       \
            const int src  = (W0) & 0xFFFFF;                                   \
            const int dlo  = ((unsigned)(W0)) >> 20;                           \
            const int comp = enc & 1;                                          \
            const float a  = __uint_as_float(enc);                             \
            const float2 ts = tmp2[src];                                       \
            const float2 td = tl[dlo];                                         \
            const float2 ic = il[dlo];                                         \
            const float tsv = comp ? ts.y : ts.x;                              \
            const float tdv = comp ? td.y : td.x;                              \
            const float icv = comp ? ic.y : ic.x;                              \
            atomicAdd(&acc[dlo], (tsv - tdv) / a * icv);                       \
        }                                                                      \
    }
    for (int i = start + (int)threadIdx.x * 2; i < end; i += PT * 2) {
        vi4 rr = __builtin_nontemporal_load((const vi4*)(ebuf + i));
        if (i >= beg)    P2REC(rr.x, rr.y)
        if (i + 1 < end) P2REC(rr.z, rr.w)
    }
    #undef P2REC

    __syncthreads();
    for (int i = threadIdx.x; i < BUCKET; i += PT) {
        const int node = lo + i;
        if (node >= N) break;
        out[node] = (acc[i] + 1.0f) * (1.0f - (float)mask[node]);
    }
}

// ---------------- fallback path (proven R5, 1042 us) ----------------

#define BLK   256
#define EPT   4
#define CHUNK (BLK * EPT)
#define GRAB  8

__device__ __forceinline__ int xcd_id() {
    return __builtin_amdgcn_s_getreg((31u << 11) | 20) & 7;
}
__device__ __forceinline__ void wg_add_d(double* p, double v) {
    __hip_atomic_fetch_add(p, v, __ATOMIC_RELAXED, __HIP_MEMORY_SCOPE_WORKGROUP);
}
__device__ __forceinline__ void wg_add_f(float* p, float v) {
    __hip_atomic_fetch_add(p, v, __ATOMIC_RELAXED, __HIP_MEMORY_SCOPE_WORKGROUP);
}

__global__ __launch_bounds__(BLK) void edge_pass1(
    const int* __restrict__ srcA, const int* __restrict__ dstA,
    const float* __restrict__ attr, const float* __restrict__ x,
    double2* __restrict__ pk, int* __restrict__ tickets,
    int E, int nchunk, int sliceSz, int N)
{
    const int xcc = xcd_id();
    const int lo  = xcc * sliceSz;
    const int w   = min(sliceSz, N - lo);
    __shared__ int s_q;
    for (;;) {
        if (threadIdx.x == 0) s_q = atomicAdd(&tickets[xcc], 1);
        __syncthreads();
        const int q = s_q;
        __syncthreads();
        if (q * GRAB >= nchunk) break;
        for (int cc = 0; cc < GRAB; ++cc) {
            const int c = q * GRAB + cc;
            if (c >= nchunk) break;
            const int base = c * CHUNK + threadIdx.x * EPT;
            if (base >= E) continue;
            vi4 sv  = __builtin_nontemporal_load((const vi4*)&srcA[base]);
            vi4 dv  = __builtin_nontemporal_load((const vi4*)&dstA[base]);
            vf4 a01 = __builtin_nontemporal_load((const vf4*)&attr[2 * base]);
            vf4 a23 = __builtin_nontemporal_load((const vf4*)&attr[2 * base + 4]);
            #define P1(S, D, AX, AY)                                                  \
                if ((unsigned)((D) - lo) < (unsigned)w) {                             \
                    float diff = x[S] - x[D];                                         \
                    if ((AX) != 0.0f) wg_add_d(&pk[D].x, (double)(diff/(AX)) + PK);   \
                    if ((AY) != 0.0f) wg_add_d(&pk[D].y, (double)(diff/(AY)) + PK);   \
                }
            P1(sv.x, dv.x, a01.x, a01.y)
            P1(sv.y, dv.y, a01.z, a01.w)
            P1(sv.z, dv.z, a23.x, a23.y)
            P1(sv.w, dv.w, a23.z, a23.w)
            #undef P1
        }
    }
}

__global__ __launch_bounds__(BLK) void node_mid(
    double2* __restrict__ pk, const float* __restrict__ a_x, int N)
{
    float4* f4 = (float4*)pk;
    for (int i = blockIdx.x * BLK + threadIdx.x; i < N; i += gridDim.x * BLK) {
        double2 p = pk[i];
        double c0 = rint(p.x * PKI);
        double c1 = rint(p.y * PKI);
        float  s0 = (float)(p.x - c0 * PK);
        float  s1 = (float)(p.y - c1 * PK);
        float  i0 = 1.0f / (float)fmax(c0, 1.0);
        float  i1 = 1.0f / (float)fmax(c1, 1.0);
        float  a  = a_x[i];
        f4[i] = make_float4(a * s0 * i0, a * s1 * i1, i0, i1);
    }
}

__global__ __launch_bounds__(BLK) void edge_pass2(
    const int* __restrict__ srcA, const int* __restrict__ dstA,
    const float* __restrict__ attr, const float4* __restrict__ tf,
    float* __restrict__ acc2, int* __restrict__ tickets,
    int E, int nchunk, int sliceSz, int N)
{
    const int xcc = xcd_id();
    const int lo  = xcc * sliceSz;
    const int w   = min(sliceSz, N - lo);
    __shared__ int s_q;
    for (;;) {
        if (threadIdx.x == 0) s_q = atomicAdd(&tickets[8 + xcc], 1);
        __syncthreads();
        const int q = s_q;
        __syncthreads();
        if (q * GRAB >= nchunk) break;
        for (int cc = 0; cc < GRAB; ++cc) {
            const int c = q * GRAB + cc;
            if (c >= nchunk) break;
            const int base = c * CHUNK + threadIdx.x * EPT;
            if (base >= E) continue;
            vi4 sv  = __builtin_nontemporal_load((const vi4*)&srcA[base]);
            vi4 dv  = __builtin_nontemporal_load((const vi4*)&dstA[base]);
            vf4 a01 = __builtin_nontemporal_load((const vf4*)&attr[2 * base]);
            vf4 a23 = __builtin_nontemporal_load((const vf4*)&attr[2 * base + 4]);
            #define P2(S, D, AX, AY)                                                  \
                if ((unsigned)((D) - lo) < (unsigned)w) {                             \
                    float4 ts = tf[S], td = tf[D];                                    \
                    float contrib = 0.0f; bool any = false;                           \
                    if ((AX) != 0.0f) { contrib += (ts.x - td.x) / (AX) * td.z; any = true; } \
                    if ((AY) != 0.0f) { contrib += (ts.y - td.y) / (AY) * td.w; any = true; } \
                    if (any) wg_add_f(&acc2[D], contrib);                             \
                }
            P2(sv.x, dv.x, a01.x, a01.y)
            P2(sv.y, dv.y, a01.z, a01.w)
            P2(sv.z, dv.z, a23.x, a23.y)
            P2(sv.w, dv.w, a23.z, a23.w)
            #undef P2
        }
    }
}

__global__ __launch_bounds__(BLK) void node_out(
    const float* __restrict__ acc2, const int* __restrict__ mask,
    float* __restrict__ out, int N)
{
    for (int i = blockIdx.x * BLK + threadIdx.x; i < N; i += gridDim.x * BLK)
        out[i] = (acc2[i] + 1.0f) * (1.0f - (float)mask[i]);
}

// ---------------- launcher ----------------

extern "C" void kernel_launch(void* const* d_in, const int* in_sizes, int n_in,
                              void* d_out, int out_size, void* d_ws, size_t ws_size,
                              hipStream_t stream)
{
    const float* x    = (const float*)d_in[0];
    const float* a_x  = (const float*)d_in[1];
    const int*   eidx = (const int*)d_in[2];
    const float* attr = (const float*)d_in[3];
    const int*   mask = (const int*)d_in[4];
    float* out = (float*)d_out;

    const int N = in_sizes[0];
    const int E = in_sizes[2] / 2;
    const int K = (N + BUCKET - 1) >> K_BSH;

    const size_t need = (size_t)E * 8 + (size_t)N * 16 + 16384;

    if (ws_size >= need && N <= (1 << 20) && K <= KMAX) {
        char* p = (char*)d_ws;
        int2*   ebuf    = (int2*)p;
        float2* tmp2    = (float2*)(p + (size_t)E * 8);
        float2* inv2    = (float2*)(p + (size_t)E * 8 + (size_t)N * 8);
        int*    counts  = (int*)(p + (size_t)E * 8 + (size_t)N * 16);
        int*    offsets = counts + KMAX;          // K+1 slots
        int*    cursors = counts + 2 * KMAX + 8;

        hipMemsetAsync(counts, 0, KMAX * sizeof(int), stream);

        const int* srcA = eidx;
        const int* dstA = eidx + E;
        const int span = (((E + SB - 1) / SB) + 3) & ~3;

        k_hist<<<HB, HT, 0, stream>>>(dstA, counts, E, K);
        k_scan<<<1, KMAX, 0, stream>>>(counts, offsets, cursors, K);
        k_scatter<<<SB, SB_T, 0, stream>>>(srcA, dstA, attr, cursors, ebuf,
                                           E, K, span);
        k_phase1<<<K, PT, 0, stream>>>(ebuf, offsets, x, a_x, tmp2, inv2, N);
        k_phase2<<<K, PT, 0, stream>>>(ebuf, offsets, tmp2, inv2, mask, out, N);
    } else {
        // proven R5 fallback (20N+64 bytes of ws)
        char* ws = (char*)d_ws;
        double2* pk      = (double2*)(ws);
        float*   acc2    = (float*)(ws + (size_t)16 * N);
        int*     tickets = (int*)(ws + (size_t)20 * N);

        hipMemsetAsync(d_ws, 0, (size_t)20 * N + 64, stream);

        const int sliceSz = (N + 7) / 8;
        const int nchunk  = (E + CHUNK - 1) / CHUNK;
        const int EGRID   = 2048;
        int ngrid = (N + BLK - 1) / BLK;
        const int NGRID   = ngrid < 2048 ? ngrid : 2048;

        edge_pass1<<<EGRID, BLK, 0, stream>>>(
            eidx, eidx + E, attr, x, pk, tickets, E, nchunk, sliceSz, N);
        node_mid<<<NGRID, BLK, 0, stream>>>(pk, a_x, N);
        edge_pass2<<<EGRID, BLK, 0, stream>>>(
            eidx, eidx + E, attr, (const float4*)pk, acc2, tickets,
            E, nchunk, sliceSz, N);
        node_out<<<NGRID, BLK, 0, stream>>>(acc2, mask, out, N);
    }
}

// Round 10
// 409.978 us; speedup vs baseline: 3.1850x; 1.0293x over previous
//
#include <hip/hip_runtime.h>

// Darcy flow graph PDE residual — bucket-binned LDS aggregation, rev 4.
// (Resubmission of R9: infra timeout, kernel never ran.)
//
// Measured: global float atomics ~17-20 G/s chip-wide (R1/R2/R5) -> bin edges
// by dst bucket once, aggregate in LDS. R8: k_scatter 146 us; BW terms only
// ~48 us -> issue/latency bound: 524K global cursor atomic-returns (~26 us
// serialized) + redundant hist sweep (dst re-read + 8M LDS atomics).
// Rev 4: k_hist persists per-block histograms [SB][KMAX] (2 MB, aliased over
// tmp2); k_scanA computes column-wise exclusive prefixes (one block/bucket,
// wave scan); k_scanB scans totals -> offsets. k_scatter = ONE sweep, zero
// global atomics, lbase loaded coalesced.
//
// Edge record (8 B): w0 = src | dlo<<20 (dlo 10 bits); w1 = attr bits with
// LSB overwritten by comp (0=x,1=y); w1==0 => invalid edge.
//
// Binned ws layout (8E + 16N + 16KB ~= 80 MB, proven fit R6-R8):
//   [0, 8E)             ebuf : int2[E]
//   [8E, 8E+8N)         tmp2 : float2[N]   (first 2 MB aliased as bhist)
//   [8E+8N, 8E+16N)     inv2 : float2[N]
//   [8E+16N, +4KB)      counts[KMAX]
//   [+4KB, +8KB)        offsets[KMAX+1]
// No memset needed: every cell is written before read.
// Fallback (ws too small): proven R5 atomic path (1042 us).

typedef int   vi2 __attribute__((ext_vector_type(2)));
typedef int   vi4 __attribute__((ext_vector_type(4)));
typedef float vf4 __attribute__((ext_vector_type(4)));

#define K_BSH  10
#define BUCKET (1 << K_BSH)        // 1024 nodes per bucket
#define KMAX   1024

#define SB   512                   // scatter/hist blocks (must be 64*8)
#define HT   512                   // hist threads
#define SB_T 512                   // scatter threads
#define PT   512                   // phase block threads

static constexpr double PK  = 68719476736.0;   // 2^36
static constexpr double PKI = 1.0 / 68719476736.0;

// ---------------- binned path ----------------

__global__ __launch_bounds__(HT) void k_hist(
    const int* __restrict__ dstA, int* __restrict__ bhist,
    int E, int K, int span)
{
    __shared__ int lh[KMAX];
    for (int i = threadIdx.x; i < K; i += HT) lh[i] = 0;
    __syncthreads();
    const int beg = blockIdx.x * span;           // span % 4 == 0
    const int end = min(beg + span, E);          // E % 4 == 0
    for (int e = beg + (int)threadIdx.x * 4; e < end; e += HT * 4) {
        vi4 d = __builtin_nontemporal_load((const vi4*)&dstA[e]);
        atomicAdd(&lh[d.x >> K_BSH], 1);
        atomicAdd(&lh[d.y >> K_BSH], 1);
        atomicAdd(&lh[d.z >> K_BSH], 1);
        atomicAdd(&lh[d.w >> K_BSH], 1);
    }
    __syncthreads();
    int* row = bhist + (size_t)blockIdx.x * KMAX;
    for (int i = threadIdx.x; i < K; i += HT) row[i] = lh[i];
}

// One block per bucket k: exclusive prefix over the SB=512 block rows
// (in place), total -> counts[k]. 64 threads x 8 rows each.
__global__ __launch_bounds__(64) void k_scanA(
    int* __restrict__ bhist, int* __restrict__ counts)
{
    const int k = blockIdx.x;
    const int t = threadIdx.x;                  // 0..63
    int v[8];
    int sum = 0;
    #pragma unroll
    for (int j = 0; j < 8; ++j) {
        v[j] = bhist[(size_t)(t * 8 + j) * KMAX + k];
        sum += v[j];
    }
    int incl = sum;
    #pragma unroll
    for (int d = 1; d < 64; d <<= 1) {
        int o = __shfl_up(incl, d, 64);
        if (t >= d) incl += o;
    }
    int excl = incl - sum;
    #pragma unroll
    for (int j = 0; j < 8; ++j) {
        const int tmp = v[j];
        bhist[(size_t)(t * 8 + j) * KMAX + k] = excl;
        excl += tmp;
    }
    if (t == 63) counts[k] = incl;
}

__global__ __launch_bounds__(KMAX) void k_scanB(
    const int* __restrict__ counts, int* __restrict__ offsets, int K)
{
    __shared__ int s[KMAX];
    const int t = threadIdx.x;
    const int v = (t < K) ? counts[t] : 0;
    s[t] = v;
    __syncthreads();
    for (int d = 1; d < KMAX; d <<= 1) {
        int add = (t >= d) ? s[t - d] : 0;
        __syncthreads();
        s[t] += add;
        __syncthreads();
    }
    if (t < K) {
        offsets[t] = s[t] - v;
        if (t == K - 1) offsets[K] = s[t];
    }
}

__global__ __launch_bounds__(SB_T) void k_scatter(
    const int* __restrict__ srcA, const int* __restrict__ dstA,
    const float* __restrict__ attr,
    const int* __restrict__ colbase,   // [SB][KMAX] excl prefixes
    const int* __restrict__ offsets,
    int2* __restrict__ ebuf,
    int E, int K, int span)
{
    __shared__ int lbase[KMAX], lcnt[KMAX];
    const int* row = colbase + (size_t)blockIdx.x * KMAX;
    for (int i = threadIdx.x; i < K; i += SB_T) {
        lbase[i] = offsets[i] + row[i];
        lcnt[i]  = 0;
    }
    __syncthreads();

    const int beg = blockIdx.x * span;
    const int end = min(beg + span, E);

    for (int e = beg + (int)threadIdx.x * 4; e < end; e += SB_T * 4) {
        vi4 s4 = __builtin_nontemporal_load((const vi4*)&srcA[e]);
        vi4 d4 = __builtin_nontemporal_load((const vi4*)&dstA[e]);
        vf4 a0 = __builtin_nontemporal_load((const vf4*)&attr[2 * e]);
        vf4 a1 = __builtin_nontemporal_load((const vf4*)&attr[2 * e + 4]);

        #define PLACE(SRC, DST, AX, AY)                                        \
        {                                                                      \
            const int k    = (DST) >> K_BSH;                                   \
            const int r    = atomicAdd(&lcnt[k], 1);                           \
            const int slot = lbase[k] + r;                                     \
            const int comp = ((AX) != 0.0f) ? 0 : 1;                           \
            const float av = comp ? (AY) : (AX);                               \
            unsigned enc = 0u;                                                 \
            if ((AX) != 0.0f || (AY) != 0.0f)                                  \
                enc = (__float_as_uint(av) & ~1u) | (unsigned)comp;            \
            const int w0 = (SRC) | (((DST) & (BUCKET - 1)) << 20);             \
            ebuf[slot] = make_int2(w0, (int)enc);                              \
        }
        PLACE(s4.x, d4.x, a0.x, a0.y)
        PLACE(s4.y, d4.y, a0.z, a0.w)
        PLACE(s4.z, d4.z, a1.x, a1.y)
        PLACE(s4.w, d4.w, a1.z, a1.w)
        #undef PLACE
    }
}

__global__ __launch_bounds__(PT) void k_phase1(
    const int2* __restrict__ ebuf, const int* __restrict__ offsets,
    const float* __restrict__ x, const float* __restrict__ a_x,
    float2* __restrict__ tmp2, float2* __restrict__ inv2, int N)
{
    __shared__ double pk0[BUCKET], pk1[BUCKET];   // sum + 2^36*cnt packed
    __shared__ float xl[BUCKET];
    const int k  = blockIdx.x;
    const int lo = k << K_BSH;
    for (int i = threadIdx.x; i < BUCKET; i += PT) {
        pk0[i] = 0.0; pk1[i] = 0.0;
        const int node = lo + i;
        xl[i] = (node < N) ? x[node] : 0.0f;
    }
    __syncthreads();
    const int beg = offsets[k], end = offsets[k + 1];
    const int start = beg & ~1;                   // 16B-aligned vi4 loads

    #define P1REC(W0, W1)                                                      \
    {                                                                          \
        const unsigned enc = (unsigned)(W1);                                   \
        if (enc != 0u) {                                                       \
            const int src  = (W0) & 0xFFFFF;                                   \
            const int dlo  = ((unsigned)(W0)) >> 20;                           \
            const float a  = __uint_as_float(enc);                             \
            const float msg = (x[src] - xl[dlo]) / a;                          \
            double* p = (enc & 1) ? pk1 : pk0;                                 \
            atomicAdd(&p[dlo], (double)msg + PK);                              \
        }                                                                      \
    }
    for (int i = start + (int)threadIdx.x * 2; i < end; i += PT * 2) {
        vi4 rr = __builtin_nontemporal_load((const vi4*)(ebuf + i));
        if (i >= beg)    P1REC(rr.x, rr.y)
        if (i + 1 < end) P1REC(rr.z, rr.w)
    }
    #undef P1REC

    __syncthreads();
    for (int i = threadIdx.x; i < BUCKET; i += PT) {
        const int node = lo + i;
        if (node >= N) break;
        const double p0 = pk0[i], p1 = pk1[i];
        const double c0 = rint(p0 * PKI);
        const double c1 = rint(p1 * PKI);
        const float  s0 = (float)(p0 - c0 * PK);
        const float  s1 = (float)(p1 - c1 * PK);
        const float  i0 = 1.0f / (float)fmax(c0, 1.0);
        const float  i1 = 1.0f / (float)fmax(c1, 1.0);
        const float  a  = a_x[node];
        float2 t; t.x = a * s0 * i0; t.y = a * s1 * i1;
        float2 v; v.x = i0; v.y = i1;
        tmp2[node] = t;
        inv2[node] = v;
    }
}

__global__ __launch_bounds__(PT) void k_phase2(
    const int2* __restrict__ ebuf, const int* __restrict__ offsets,
    const float2* __restrict__ tmp2, const float2* __restrict__ inv2,
    const int* __restrict__ mask,
    float* __restrict__ out, int N)
{
    __shared__ float acc[BUCKET];
    __shared__ float2 tl[BUCKET], il[BUCKET];
    const int k  = blockIdx.x;
    const int lo = k << K_BSH;
    for (int i = threadIdx.x; i < BUCKET; i += PT) {
        acc[i] = 0.0f;
        const int node = lo + i;
        if (node < N) { tl[i] = tmp2[node]; il[i] = inv2[node]; }
        else          { tl[i] = make_float2(0.f, 0.f); il[i] = make_float2(0.f, 0.f); }
    }
    __syncthreads();
    const int beg = offsets[k], end = offsets[k + 1];
    const int start = beg & ~1;

    #define P2REC(W0, W1)                                                      \
    {                                                                          \
        const unsigned enc = (unsigned)(W1);                                   \
        if (enc != 0u) {                                                       \
            const int src  = (W0) & 0xFFFFF;                                   \
            const int dlo  = ((unsigned)(W0)) >> 20;                           \
            const int comp = enc & 1;                                          \
            const float a  = __uint_as_float(enc);                             \
            const float2 ts = tmp2[src];                                       \
            const float2 td = tl[dlo];                                         \
            const float2 ic = il[dlo];                                         \
            const float tsv = comp ? ts.y : ts.x;                              \
            const float tdv = comp ? td.y : td.x;                              \
            const float icv = comp ? ic.y : ic.x;                              \
            atomicAdd(&acc[dlo], (tsv - tdv) / a * icv);                       \
        }                                                                      \
    }
    for (int i = start + (int)threadIdx.x * 2; i < end; i += PT * 2) {
        vi4 rr = __builtin_nontemporal_load((const vi4*)(ebuf + i));
        if (i >= beg)    P2REC(rr.x, rr.y)
        if (i + 1 < end) P2REC(rr.z, rr.w)
    }
    #undef P2REC

    __syncthreads();
    for (int i = threadIdx.x; i < BUCKET; i += PT) {
        const int node = lo + i;
        if (node >= N) break;
        out[node] = (acc[i] + 1.0f) * (1.0f - (float)mask[node]);
    }
}

// ---------------- fallback path (proven R5, 1042 us) ----------------

#define BLK   256
#define EPT   4
#define CHUNK (BLK * EPT)
#define GRAB  8

__device__ __forceinline__ int xcd_id() {
    return __builtin_amdgcn_s_getreg((31u << 11) | 20) & 7;
}
__device__ __forceinline__ void wg_add_d(double* p, double v) {
    __hip_atomic_fetch_add(p, v, __ATOMIC_RELAXED, __HIP_MEMORY_SCOPE_WORKGROUP);
}
__device__ __forceinline__ void wg_add_f(float* p, float v) {
    __hip_atomic_fetch_add(p, v, __ATOMIC_RELAXED, __HIP_MEMORY_SCOPE_WORKGROUP);
}

__global__ __launch_bounds__(BLK) void edge_pass1(
    const int* __restrict__ srcA, const int* __restrict__ dstA,
    const float* __restrict__ attr, const float* __restrict__ x,
    double2* __restrict__ pk, int* __restrict__ tickets,
    int E, int nchunk, int sliceSz, int N)
{
    const int xcc = xcd_id();
    const int lo  = xcc * sliceSz;
    const int w   = min(sliceSz, N - lo);
    __shared__ int s_q;
    for (;;) {
        if (threadIdx.x == 0) s_q = atomicAdd(&tickets[xcc], 1);
        __syncthreads();
        const int q = s_q;
        __syncthreads();
        if (q * GRAB >= nchunk) break;
        for (int cc = 0; cc < GRAB; ++cc) {
            const int c = q * GRAB + cc;
            if (c >= nchunk) break;
            const int base = c * CHUNK + threadIdx.x * EPT;
            if (base >= E) continue;
            vi4 sv  = __builtin_nontemporal_load((const vi4*)&srcA[base]);
            vi4 dv  = __builtin_nontemporal_load((const vi4*)&dstA[base]);
            vf4 a01 = __builtin_nontemporal_load((const vf4*)&attr[2 * base]);
            vf4 a23 = __builtin_nontemporal_load((const vf4*)&attr[2 * base + 4]);
            #define P1(S, D, AX, AY)                                                  \
                if ((unsigned)((D) - lo) < (unsigned)w) {                             \
                    float diff = x[S] - x[D];                                         \
                    if ((AX) != 0.0f) wg_add_d(&pk[D].x, (double)(diff/(AX)) + PK);   \
                    if ((AY) != 0.0f) wg_add_d(&pk[D].y, (double)(diff/(AY)) + PK);   \
                }
            P1(sv.x, dv.x, a01.x, a01.y)
            P1(sv.y, dv.y, a01.z, a01.w)
            P1(sv.z, dv.z, a23.x, a23.y)
            P1(sv.w, dv.w, a23.z, a23.w)
            #undef P1
        }
    }
}

__global__ __launch_bounds__(BLK) void node_mid(
    double2* __restrict__ pk, const float* __restrict__ a_x, int N)
{
    float4* f4 = (float4*)pk;
    for (int i = blockIdx.x * BLK + threadIdx.x; i < N; i += gridDim.x * BLK) {
        double2 p = pk[i];
        double c0 = rint(p.x * PKI);
        double c1 = rint(p.y * PKI);
        float  s0 = (float)(p.x - c0 * PK);
        float  s1 = (float)(p.y - c1 * PK);
        float  i0 = 1.0f / (float)fmax(c0, 1.0);
        float  i1 = 1.0f / (float)fmax(c1, 1.0);
        float  a  = a_x[i];
        f4[i] = make_float4(a * s0 * i0, a * s1 * i1, i0, i1);
    }
}

__global__ __launch_bounds__(BLK) void edge_pass2(
    const int* __restrict__ srcA, const int* __restrict__ dstA,
    const float* __restrict__ attr, const float4* __restrict__ tf,
    float* __restrict__ acc2, int* __restrict__ tickets,
    int E, int nchunk, int sliceSz, int N)
{
    const int xcc = xcd_id();
    const int lo  = xcc * sliceSz;
    const int w   = min(sliceSz, N - lo);
    __shared__ int s_q;
    for (;;) {
        if (threadIdx.x == 0) s_q = atomicAdd(&tickets[8 + xcc], 1);
        __syncthreads();
        const int q = s_q;
        __syncthreads();
        if (q * GRAB >= nchunk) break;
        for (int cc = 0; cc < GRAB; ++cc) {
            const int c = q * GRAB + cc;
            if (c >= nchunk) break;
            const int base = c * CHUNK + threadIdx.x * EPT;
            if (base >= E) continue;
            vi4 sv  = __builtin_nontemporal_load((const vi4*)&srcA[base]);
            vi4 dv  = __builtin_nontemporal_load((const vi4*)&dstA[base]);
            vf4 a01 = __builtin_nontemporal_load((const vf4*)&attr[2 * base]);
            vf4 a23 = __builtin_nontemporal_load((const vf4*)&attr[2 * base + 4]);
            #define P2(S, D, AX, AY)                                                  \
                if ((unsigned)((D) - lo) < (unsigned)w) {                             \
                    float4 ts = tf[S], td = tf[D];                                    \
                    float contrib = 0.0f; bool any = false;                           \
                    if ((AX) != 0.0f) { contrib += (ts.x - td.x) / (AX) * td.z; any = true; } \
                    if ((AY) != 0.0f) { contrib += (ts.y - td.y) / (AY) * td.w; any = true; } \
                    if (any) wg_add_f(&acc2[D], contrib);                             \
                }
            P2(sv.x, dv.x, a01.x, a01.y)
            P2(sv.y, dv.y, a01.z, a01.w)
            P2(sv.z, dv.z, a23.x, a23.y)
            P2(sv.w, dv.w, a23.z, a23.w)
            #undef P2
        }
    }
}

__global__ __launch_bounds__(BLK) void node_out(
    const float* __restrict__ acc2, const int* __restrict__ mask,
    float* __restrict__ out, int N)
{
    for (int i = blockIdx.x * BLK + threadIdx.x; i < N; i += gridDim.x * BLK)
        out[i] = (acc2[i] + 1.0f) * (1.0f - (float)mask[i]);
}

// ---------------- launcher ----------------

extern "C" void kernel_launch(void* const* d_in, const int* in_sizes, int n_in,
                              void* d_out, int out_size, void* d_ws, size_t ws_size,
                              hipStream_t stream)
{
    const float* x    = (const float*)d_in[0];
    const float* a_x  = (const float*)d_in[1];
    const int*   eidx = (const int*)d_in[2];
    const float* attr = (const float*)d_in[3];
    const int*   mask = (const int*)d_in[4];
    float* out = (float*)d_out;

    const int N = in_sizes[0];
    const int E = in_sizes[2] / 2;
    const int K = (N + BUCKET - 1) >> K_BSH;

    const size_t need = (size_t)E * 8 + (size_t)N * 16 + 16384;
    const size_t bhist_bytes = (size_t)SB * KMAX * 4;   // 2 MB

    if (ws_size >= need && N <= (1 << 20) && K <= KMAX &&
        bhist_bytes <= (size_t)N * 8) {
        char* p = (char*)d_ws;
        int2*   ebuf    = (int2*)p;
        float2* tmp2    = (float2*)(p + (size_t)E * 8);
        float2* inv2    = (float2*)(p + (size_t)E * 8 + (size_t)N * 8);
        int*    counts  = (int*)(p + (size_t)E * 8 + (size_t)N * 16);
        int*    offsets = counts + KMAX;          // K+1 slots
        int*    bhist   = (int*)tmp2;             // aliased: dead until phase1

        const int* srcA = eidx;
        const int* dstA = eidx + E;
        const int span = (((E + SB - 1) / SB) + 3) & ~3;

        k_hist<<<SB, HT, 0, stream>>>(dstA, bhist, E, K, span);
        k_scanA<<<K, 64, 0, stream>>>(bhist, counts);
        k_scanB<<<1, KMAX, 0, stream>>>(counts, offsets, K);
        k_scatter<<<SB, SB_T, 0, stream>>>(srcA, dstA, attr, bhist, offsets,
                                           ebuf, E, K, span);
        k_phase1<<<K, PT, 0, stream>>>(ebuf, offsets, x, a_x, tmp2, inv2, N);
        k_phase2<<<K, PT, 0, stream>>>(ebuf, offsets, tmp2, inv2, mask, out, N);
    } else {
        // proven R5 fallback (20N+64 bytes of ws)
        char* ws = (char*)d_ws;
        double2* pk      = (double2*)(ws);
        float*   acc2    = (float*)(ws + (size_t)16 * N);
        int*     tickets = (int*)(ws + (size_t)20 * N);

        hipMemsetAsync(d_ws, 0, (size_t)20 * N + 64, stream);

        const int sliceSz = (N + 7) / 8;
        const int nchunk  = (E + CHUNK - 1) / CHUNK;
        const int EGRID   = 2048;
        int ngrid = (N + BLK - 1) / BLK;
        const int NGRID   = ngrid < 2048 ? ngrid : 2048;

        edge_pass1<<<EGRID, BLK, 0, stream>>>(
            eidx, eidx + E, attr, x, pk, tickets, E, nchunk, sliceSz, N);
        node_mid<<<NGRID, BLK, 0, stream>>>(pk, a_x, N);
        edge_pass2<<<EGRID, BLK, 0, stream>>>(
            eidx, eidx + E, attr, (const float4*)pk, acc2, tickets,
            E, nchunk, sliceSz, N);
        node_out<<<NGRID, BLK, 0, stream>>>(acc2, mask, out, N);
    }
}

// Round 11
// 370.637 us; speedup vs baseline: 3.5230x; 1.1061x over previous
//
#include <hip/hip_runtime.h>

// Darcy flow graph PDE residual — bucket-binned LDS aggregation, rev 5.
//
// Measured history: global float atomics ~17-20 G/s (R1/R2/R5). R10: k_scatter
// 137 us with WRITE_SIZE 212 MB for a 64 MB payload -> 3.3x write amplification
// from randomly-ordered 8 B stores across 1024 bucket regions (L2 evicts
// partially-dirty lines). Rev 5: stage each block's records in LDS, binned
// bucket-contiguous via an in-block scan, then flush per-bucket runs with
// lane-contiguous stores (full-line writes).
//
// Edge record (8 B): w0 = src | dlo<<20 (dlo 10 bits); w1 = attr bits with
// LSB overwritten by comp (0=x,1=y); w1==0 => invalid edge.
//
// Binned ws layout (8E + 16N + 16KB ~= 80 MB, proven fit R6-R10):
//   [0, 8E)             ebuf : int2[E]
//   [8E, 8E+8N)         tmp2 : float2[N]   (first 4 MB aliased as bhist)
//   [8E+8N, 8E+16N)     inv2 : float2[N]
//   [8E+16N, +4KB)      counts[KMAX]
//   [+4KB, +8KB)        offsets[KMAX+1]
// Fallback (ws too small): proven R5 atomic path (1042 us).

typedef int   vi2 __attribute__((ext_vector_type(2)));
typedef int   vi4 __attribute__((ext_vector_type(4)));
typedef float vf4 __attribute__((ext_vector_type(4)));

#define K_BSH  10
#define BUCKET (1 << K_BSH)        // 1024 nodes per bucket
#define KMAX   1024

#define SB   1024                  // scatter/hist blocks
#define HT   512                   // hist threads
#define SB_T 512                   // scatter threads
#define SREC_CAP 8192              // LDS record stage per block (64 KB)
#define PT   512                   // phase block threads

static constexpr double PK  = 68719476736.0;   // 2^36
static constexpr double PKI = 1.0 / 68719476736.0;

// ---------------- binned path ----------------

__global__ __launch_bounds__(HT) void k_hist(
    const int* __restrict__ dstA, int* __restrict__ bhist,
    int E, int K, int span)
{
    __shared__ int lh[KMAX];
    for (int i = threadIdx.x; i < K; i += HT) lh[i] = 0;
    __syncthreads();
    const int beg = blockIdx.x * span;           // span % 4 == 0
    const int end = min(beg + span, E);          // E % 4 == 0
    for (int e = beg + (int)threadIdx.x * 4; e < end; e += HT * 4) {
        vi4 d = __builtin_nontemporal_load((const vi4*)&dstA[e]);
        atomicAdd(&lh[d.x >> K_BSH], 1);
        atomicAdd(&lh[d.y >> K_BSH], 1);
        atomicAdd(&lh[d.z >> K_BSH], 1);
        atomicAdd(&lh[d.w >> K_BSH], 1);
    }
    __syncthreads();
    int* row = bhist + (size_t)blockIdx.x * KMAX;
    for (int i = threadIdx.x; i < K; i += HT) row[i] = lh[i];
}

// One block per bucket k: exclusive prefix over the SB=1024 block rows
// (in place), total -> counts[k]. 64 threads x 16 rows each.
__global__ __launch_bounds__(64) void k_scanA(
    int* __restrict__ bhist, int* __restrict__ counts)
{
    const int k = blockIdx.x;
    const int t = threadIdx.x;                  // 0..63
    int v[16];
    int sum = 0;
    #pragma unroll
    for (int j = 0; j < 16; ++j) {
        v[j] = bhist[(size_t)(t * 16 + j) * KMAX + k];
        sum += v[j];
    }
    int incl = sum;
    #pragma unroll
    for (int d = 1; d < 64; d <<= 1) {
        int o = __shfl_up(incl, d, 64);
        if (t >= d) incl += o;
    }
    int excl = incl - sum;
    #pragma unroll
    for (int j = 0; j < 16; ++j) {
        const int tmp = v[j];
        bhist[(size_t)(t * 16 + j) * KMAX + k] = excl;
        excl += tmp;
    }
    if (t == 63) counts[k] = incl;
}

__global__ __launch_bounds__(KMAX) void k_scanB(
    const int* __restrict__ counts, int* __restrict__ offsets, int K)
{
    __shared__ int s[KMAX];
    const int t = threadIdx.x;
    const int v = (t < K) ? counts[t] : 0;
    s[t] = v;
    __syncthreads();
    for (int d = 1; d < KMAX; d <<= 1) {
        int add = (t >= d) ? s[t - d] : 0;
        __syncthreads();
        s[t] += add;
        __syncthreads();
    }
    if (t < K) {
        offsets[t] = s[t] - v;
        if (t == K - 1) offsets[K] = s[t];
    }
}

// LDS-staged scatter: records binned bucket-contiguous in LDS, flushed as
// dense per-bucket runs -> full-line global writes (kills write amplification).
__global__ __launch_bounds__(SB_T) void k_scatter(
    const int* __restrict__ srcA, const int* __restrict__ dstA,
    const float* __restrict__ attr,
    const int* __restrict__ colbase,   // [SB][KMAX] excl prefixes
    const int* __restrict__ offsets,
    int2* __restrict__ ebuf,
    int E, int K, int span)
{
    __shared__ int2 srec[SREC_CAP];            // 64 KB record stage
    __shared__ int  lpre[KMAX];                // hist -> local excl prefix
    __shared__ int  lcnt[KMAX];
    __shared__ int  lbase[KMAX];               // global base per bucket
    __shared__ int  wsum[8];

    const int tid  = threadIdx.x;
    const int lane = tid & 63;
    const int wid  = tid >> 6;                 // 8 waves
    const int* row = colbase + (size_t)blockIdx.x * KMAX;

    for (int i = tid; i < KMAX; i += SB_T) {
        lpre[i]  = 0;
        lcnt[i]  = 0;
        lbase[i] = offsets[i] + row[i];        // i>=K unused (cnt 0)
    }
    __syncthreads();

    const int beg = blockIdx.x * span;
    const int end = min(beg + span, E);

    // sweep A: block-local histogram
    for (int e = beg + tid * 4; e < end; e += SB_T * 4) {
        vi4 d = *(const vi4*)&dstA[e];
        atomicAdd(&lpre[d.x >> K_BSH], 1);
        atomicAdd(&lpre[d.y >> K_BSH], 1);
        atomicAdd(&lpre[d.z >> K_BSH], 1);
        atomicAdd(&lpre[d.w >> K_BSH], 1);
    }
    __syncthreads();

    // in-block exclusive scan of lpre[1024] (in place). 512 thr x 2 cells.
    {
        const int a0 = lpre[2 * tid], a1 = lpre[2 * tid + 1];
        int psum = a0 + a1;
        int incl = psum;
        #pragma unroll
        for (int d = 1; d < 64; d <<= 1) {
            int o = __shfl_up(incl, d, 64);
            if (lane >= d) incl += o;
        }
        if (lane == 63) wsum[wid] = incl;
        __syncthreads();
        if (tid == 0) {
            int run = 0;
            #pragma unroll
            for (int w = 0; w < 8; ++w) { int t2 = wsum[w]; wsum[w] = run; run += t2; }
        }
        __syncthreads();
        const int excl = wsum[wid] + incl - psum;
        lpre[2 * tid]     = excl;
        lpre[2 * tid + 1] = excl + a0;
    }
    __syncthreads();

    // sweep B: re-read (L2-hot), encode, place into LDS slot
    for (int e = beg + tid * 4; e < end; e += SB_T * 4) {
        vi4 s4 = *(const vi4*)&srcA[e];
        vi4 d4 = *(const vi4*)&dstA[e];
        vf4 a0 = *(const vf4*)&attr[2 * e];
        vf4 a1 = *(const vf4*)&attr[2 * e + 4];

        #define PLACE(SRC, DST, AX, AY)                                        \
        {                                                                      \
            const int k    = (DST) >> K_BSH;                                   \
            const int r    = atomicAdd(&lcnt[k], 1);                           \
            const int slot = lpre[k] + r;                                      \
            const int comp = ((AX) != 0.0f) ? 0 : 1;                           \
            const float av = comp ? (AY) : (AX);                               \
            unsigned enc = 0u;                                                 \
            if ((AX) != 0.0f || (AY) != 0.0f)                                  \
                enc = (__float_as_uint(av) & ~1u) | (unsigned)comp;            \
            const int w0 = (SRC) | (((DST) & (BUCKET - 1)) << 20);             \
            srec[slot] = make_int2(w0, (int)enc);                              \
        }
        PLACE(s4.x, d4.x, a0.x, a0.y)
        PLACE(s4.y, d4.y, a0.z, a0.w)
        PLACE(s4.z, d4.z, a1.x, a1.y)
        PLACE(s4.w, d4.w, a1.z, a1.w)
        #undef PLACE
    }
    __syncthreads();

    // flush: wave w owns buckets [w*128, w*128+128); dense coalesced stores
    const int kbeg = wid * (KMAX / 8);
    for (int k = kbeg; k < kbeg + (KMAX / 8); ++k) {
        const int cnt = lcnt[k];
        if (cnt == 0) continue;
        const int lp = lpre[k];
        const int gb = lbase[k];
        for (int i = lane; i < cnt; i += 64)
            ebuf[gb + i] = srec[lp + i];
    }
}

__global__ __launch_bounds__(PT) void k_phase1(
    const int2* __restrict__ ebuf, const int* __restrict__ offsets,
    const float* __restrict__ x, const float* __restrict__ a_x,
    float2* __restrict__ tmp2, float2* __restrict__ inv2, int N)
{
    __shared__ double pk0[BUCKET], pk1[BUCKET];   // sum + 2^36*cnt packed
    __shared__ float xl[BUCKET];
    const int k  = blockIdx.x;
    const int lo = k << K_BSH;
    for (int i = threadIdx.x; i < BUCKET; i += PT) {
        pk0[i] = 0.0; pk1[i] = 0.0;
        const int node = lo + i;
        xl[i] = (node < N) ? x[node] : 0.0f;
    }
    __syncthreads();
    const int beg = offsets[k], end = offsets[k + 1];
    const int start = beg & ~1;                   // 16B-aligned vi4 loads

    #define P1REC(W0, W1)                                                      \
    {                                                                          \
        const unsigned enc = (unsigned)(W1);                                   \
        if (enc != 0u) {                                                       \
            const int src  = (W0) & 0xFFFFF;                                   \
            const int dlo  = ((unsigned)(W0)) >> 20;                           \
            const float a  = __uint_as_float(enc);                             \
            const float msg = (x[src] - xl[dlo]) / a;                          \
            double* p = (enc & 1) ? pk1 : pk0;                                 \
            atomicAdd(&p[dlo], (double)msg + PK);                              \
        }                                                                      \
    }
    for (int i = start + (int)threadIdx.x * 2; i < end; i += PT * 2) {
        vi4 rr = __builtin_nontemporal_load((const vi4*)(ebuf + i));
        if (i >= beg)    P1REC(rr.x, rr.y)
        if (i + 1 < end) P1REC(rr.z, rr.w)
    }
    #undef P1REC

    __syncthreads();
    for (int i = threadIdx.x; i < BUCKET; i += PT) {
        const int node = lo + i;
        if (node >= N) break;
        const double p0 = pk0[i], p1 = pk1[i];
        const double c0 = rint(p0 * PKI);
        const double c1 = rint(p1 * PKI);
        const float  s0 = (float)(p0 - c0 * PK);
        const float  s1 = (float)(p1 - c1 * PK);
        const float  i0 = 1.0f / (float)fmax(c0, 1.0);
        const float  i1 = 1.0f / (float)fmax(c1, 1.0);
        const float  a  = a_x[node];
        float2 t; t.x = a * s0 * i0; t.y = a * s1 * i1;
        float2 v; v.x = i0; v.y = i1;
        tmp2[node] = t;
        inv2[node] = v;
    }
}

__global__ __launch_bounds__(PT) void k_phase2(
    const int2* __restrict__ ebuf, const int* __restrict__ offsets,
    const float2* __restrict__ tmp2, const float2* __restrict__ inv2,
    const int* __restrict__ mask,
    float* __restrict__ out, int N)
{
    __shared__ float acc[BUCKET];
    __shared__ float2 tl[BUCKET], il[BUCKET];
    const int k  = blockIdx.x;
    const int lo = k << K_BSH;
    for (int i = threadIdx.x; i < BUCKET; i += PT) {
        acc[i] = 0.0f;
        const int node = lo + i;
        if (node < N) { tl[i] = tmp2[node]; il[i] = inv2[node]; }
        else          { tl[i] = make_float2(0.f, 0.f); il[i] = make_float2(0.f, 0.f); }
    }
    __syncthreads();
    const int beg = offsets[k], end = offsets[k + 1];
    const int start = beg & ~1;

    #define P2REC(W0, W1)                                                      \
    {                                                                          \
        const unsigned enc = (unsigned)(W1);                                   \
        if (enc != 0u) {                                                       \
            const int src  = (W0) & 0xFFFFF;                                   \
            const int dlo  = ((unsigned)(W0)) >> 20;                           \
            const int comp = enc & 1;                                          \
            const float a  = __uint_as_float(enc);                             \
            const float2 ts = tmp2[src];                                       \
            const float2 td = tl[dlo];                                         \
            const float2 ic = il[dlo];                                         \
            const float tsv = comp ? ts.y : ts.x;                              \
            const float tdv = comp ? td.y : td.x;                              \
            const float icv = comp ? ic.y : ic.x;                              \
            atomicAdd(&acc[dlo], (tsv - tdv) / a * icv);                       \
        }                                                                      \
    }
    for (int i = start + (int)threadIdx.x * 2; i < end; i += PT * 2) {
        vi4 rr = __builtin_nontemporal_load((const vi4*)(ebuf + i));
        if (i >= beg)    P2REC(rr.x, rr.y)
        if (i + 1 < end) P2REC(rr.z, rr.w)
    }
    #undef P2REC

    __syncthreads();
    for (int i = threadIdx.x; i < BUCKET; i += PT) {
        const int node = lo + i;
        if (node >= N) break;
        out[node] = (acc[i] + 1.0f) * (1.0f - (float)mask[node]);
    }
}

// ---------------- fallback path (proven R5, 1042 us) ----------------

#define BLK   256
#define EPT   4
#define CHUNK (BLK * EPT)
#define GRAB  8

__device__ __forceinline__ int xcd_id() {
    return __builtin_amdgcn_s_getreg((31u << 11) | 20) & 7;
}
__device__ __forceinline__ void wg_add_d(double* p, double v) {
    __hip_atomic_fetch_add(p, v, __ATOMIC_RELAXED, __HIP_MEMORY_SCOPE_WORKGROUP);
}
__device__ __forceinline__ void wg_add_f(float* p, float v) {
    __hip_atomic_fetch_add(p, v, __ATOMIC_RELAXED, __HIP_MEMORY_SCOPE_WORKGROUP);
}

__global__ __launch_bounds__(BLK) void edge_pass1(
    const int* __restrict__ srcA, const int* __restrict__ dstA,
    const float* __restrict__ attr, const float* __restrict__ x,
    double2* __restrict__ pk, int* __restrict__ tickets,
    int E, int nchunk, int sliceSz, int N)
{
    const int xcc = xcd_id();
    const int lo  = xcc * sliceSz;
    const int w   = min(sliceSz, N - lo);
    __shared__ int s_q;
    for (;;) {
        if (threadIdx.x == 0) s_q = atomicAdd(&tickets[xcc], 1);
        __syncthreads();
        const int q = s_q;
        __syncthreads();
        if (q * GRAB >= nchunk) break;
        for (int cc = 0; cc < GRAB; ++cc) {
            const int c = q * GRAB + cc;
            if (c >= nchunk) break;
            const int base = c * CHUNK + threadIdx.x * EPT;
            if (base >= E) continue;
            vi4 sv  = __builtin_nontemporal_load((const vi4*)&srcA[base]);
            vi4 dv  = __builtin_nontemporal_load((const vi4*)&dstA[base]);
            vf4 a01 = __builtin_nontemporal_load((const vf4*)&attr[2 * base]);
            vf4 a23 = __builtin_nontemporal_load((const vf4*)&attr[2 * base + 4]);
            #define P1(S, D, AX, AY)                                                  \
                if ((unsigned)((D) - lo) < (unsigned)w) {                             \
                    float diff = x[S] - x[D];                                         \
                    if ((AX) != 0.0f) wg_add_d(&pk[D].x, (double)(diff/(AX)) + PK);   \
                    if ((AY) != 0.0f) wg_add_d(&pk[D].y, (double)(diff/(AY)) + PK);   \
                }
            P1(sv.x, dv.x, a01.x, a01.y)
            P1(sv.y, dv.y, a01.z, a01.w)
            P1(sv.z, dv.z, a23.x, a23.y)
            P1(sv.w, dv.w, a23.z, a23.w)
            #undef P1
        }
    }
}

__global__ __launch_bounds__(BLK) void node_mid(
    double2* __restrict__ pk, const float* __restrict__ a_x, int N)
{
    float4* f4 = (float4*)pk;
    for (int i = blockIdx.x * BLK + threadIdx.x; i < N; i += gridDim.x * BLK) {
        double2 p = pk[i];
        double c0 = rint(p.x * PKI);
        double c1 = rint(p.y * PKI);
        float  s0 = (float)(p.x - c0 * PK);
        float  s1 = (float)(p.y - c1 * PK);
        float  i0 = 1.0f / (float)fmax(c0, 1.0);
        float  i1 = 1.0f / (float)fmax(c1, 1.0);
        float  a  = a_x[i];
        f4[i] = make_float4(a * s0 * i0, a * s1 * i1, i0, i1);
    }
}

__global__ __launch_bounds__(BLK) void edge_pass2(
    const int* __restrict__ srcA, const int* __restrict__ dstA,
    const float* __restrict__ attr, const float4* __restrict__ tf,
    float* __restrict__ acc2, int* __restrict__ tickets,
    int E, int nchunk, int sliceSz, int N)
{
    const int xcc = xcd_id();
    const int lo  = xcc * sliceSz;
    const int w   = min(sliceSz, N - lo);
    __shared__ int s_q;
    for (;;) {
        if (threadIdx.x == 0) s_q = atomicAdd(&tickets[8 + xcc], 1);
        __syncthreads();
        const int q = s_q;
        __syncthreads();
        if (q * GRAB >= nchunk) break;
        for (int cc = 0; cc < GRAB; ++cc) {
            const int c = q * GRAB + cc;
            if (c >= nchunk) break;
            const int base = c * CHUNK + threadIdx.x * EPT;
            if (base >= E) continue;
            vi4 sv  = __builtin_nontemporal_load((const vi4*)&srcA[base]);
            vi4 dv  = __builtin_nontemporal_load((const vi4*)&dstA[base]);
            vf4 a01 = __builtin_nontemporal_load((const vf4*)&attr[2 * base]);
            vf4 a23 = __builtin_nontemporal_load((const vf4*)&attr[2 * base + 4]);
            #define P2(S, D, AX, AY)                                                  \
                if ((unsigned)((D) - lo) < (unsigned)w) {                             \
                    float4 ts = tf[S], td = tf[D];                                    \
                    float contrib = 0.0f; bool any = false;                           \
                    if ((AX) != 0.0f) { contrib += (ts.x - td.x) / (AX) * td.z; any = true; } \
                    if ((AY) != 0.0f) { contrib += (ts.y - td.y) / (AY) * td.w; any = true; } \
                    if (any) wg_add_f(&acc2[D], contrib);                             \
                }
            P2(sv.x, dv.x, a01.x, a01.y)
            P2(sv.y, dv.y, a01.z, a01.w)
            P2(sv.z, dv.z, a23.x, a23.y)
            P2(sv.w, dv.w, a23.z, a23.w)
            #undef P2
        }
    }
}

__global__ __launch_bounds__(BLK) void node_out(
    const float* __restrict__ acc2, const int* __restrict__ mask,
    float* __restrict__ out, int N)
{
    for (int i = blockIdx.x * BLK + threadIdx.x; i < N; i += gridDim.x * BLK)
        out[i] = (acc2[i] + 1.0f) * (1.0f - (float)mask[i]);
}

// ---------------- launcher ----------------

extern "C" void kernel_launch(void* const* d_in, const int* in_sizes, int n_in,
                              void* d_out, int out_size, void* d_ws, size_t ws_size,
                              hipStream_t stream)
{
    const float* x    = (const float*)d_in[0];
    const float* a_x  = (const float*)d_in[1];
    const int*   eidx = (const int*)d_in[2];
    const float* attr = (const float*)d_in[3];
    const int*   mask = (const int*)d_in[4];
    float* out = (float*)d_out;

    const int N = in_sizes[0];
    const int E = in_sizes[2] / 2;
    const int K = (N + BUCKET - 1) >> K_BSH;

    const size_t need = (size_t)E * 8 + (size_t)N * 16 + 16384;
    const size_t bhist_bytes = (size_t)SB * KMAX * 4;   // 4 MB
    const int span = (((E + SB - 1) / SB) + 3) & ~3;

    if (ws_size >= need && N <= (1 << 20) && K <= KMAX &&
        bhist_bytes <= (size_t)N * 8 && span <= SREC_CAP) {
        char* p = (char*)d_ws;
        int2*   ebuf    = (int2*)p;
        float2* tmp2    = (float2*)(p + (size_t)E * 8);
        float2* inv2    = (float2*)(p + (size_t)E * 8 + (size_t)N * 8);
        int*    counts  = (int*)(p + (size_t)E * 8 + (size_t)N * 16);
        int*    offsets = counts + KMAX;          // K+1 slots
        int*    bhist   = (int*)tmp2;             // aliased: dead until phase1

        const int* srcA = eidx;
        const int* dstA = eidx + E;

        k_hist<<<SB, HT, 0, stream>>>(dstA, bhist, E, K, span);
        k_scanA<<<K, 64, 0, stream>>>(bhist, counts);
        k_scanB<<<1, KMAX, 0, stream>>>(counts, offsets, K);
        k_scatter<<<SB, SB_T, 0, stream>>>(srcA, dstA, attr, bhist, offsets,
                                           ebuf, E, K, span);
        k_phase1<<<K, PT, 0, stream>>>(ebuf, offsets, x, a_x, tmp2, inv2, N);
        k_phase2<<<K, PT, 0, stream>>>(ebuf, offsets, tmp2, inv2, mask, out, N);
    } else {
        // proven R5 fallback (20N+64 bytes of ws)
        char* ws = (char*)d_ws;
        double2* pk      = (double2*)(ws);
        float*   acc2    = (float*)(ws + (size_t)16 * N);
        int*     tickets = (int*)(ws + (size_t)20 * N);

        hipMemsetAsync(d_ws, 0, (size_t)20 * N + 64, stream);

        const int sliceSz = (N + 7) / 8;
        const int nchunk  = (E + CHUNK - 1) / CHUNK;
        const int EGRID   = 2048;
        int ngrid = (N + BLK - 1) / BLK;
        const int NGRID   = ngrid < 2048 ? ngrid : 2048;

        edge_pass1<<<EGRID, BLK, 0, stream>>>(
            eidx, eidx + E, attr, x, pk, tickets, E, nchunk, sliceSz, N);
        node_mid<<<NGRID, BLK, 0, stream>>>(pk, a_x, N);
        edge_pass2<<<EGRID, BLK, 0, stream>>>(
            eidx, eidx + E, attr, (const float4*)pk, acc2, tickets,
            E, nchunk, sliceSz, N);
        node_out<<<NGRID, BLK, 0, stream>>>(acc2, mask, out, N);
    }
}

// Round 12
// 365.778 us; speedup vs baseline: 3.5698x; 1.0133x over previous
//
#include <hip/hip_runtime.h>

// Darcy flow graph PDE residual — bucket-binned LDS aggregation, rev 6.
//
// Measured history: global float atomics ~17-20 G/s (R1/R2/R5); scattered
// 8 B stores suffer 3.3x write amplification (R10) fixed by LDS-staged
// write combining (R11: scatter 137->96 us, WRITE 212->86 MB).
// Rev 6: (a) scatter's sweep-A histogram is redundant — reconstruct the
// block-local histogram from scanA's prefix table: h[b][k] =
// colbase[b+1][k]-colbase[b][k] (last block: counts[k]-colbase[b][k]).
// Saves a 32 MB dst read + 8M LDS atomics + barrier. (b) phases process
// 4 records/thread/iter (2x vi4) to double gather MLP.
//
// Edge record (8 B): w0 = src | dlo<<20 (dlo 10 bits); w1 = attr bits with
// LSB overwritten by comp (0=x,1=y); w1==0 => invalid edge.
//
// Binned ws layout (8E + 16N + 16KB ~= 80 MB, proven fit R6-R11):
//   [0, 8E)             ebuf : int2[E]
//   [8E, 8E+8N)         tmp2 : float2[N]   (first 4 MB aliased as bhist)
//   [8E+8N, 8E+16N)     inv2 : float2[N]
//   [8E+16N, +4KB)      counts[KMAX]
//   [+4KB, +8KB)        offsets[KMAX+1]
// Fallback (ws too small): proven R5 atomic path (1042 us).

typedef int   vi2 __attribute__((ext_vector_type(2)));
typedef int   vi4 __attribute__((ext_vector_type(4)));
typedef float vf4 __attribute__((ext_vector_type(4)));

#define K_BSH  10
#define BUCKET (1 << K_BSH)        // 1024 nodes per bucket
#define KMAX   1024

#define SB   1024                  // scatter/hist blocks
#define HT   512                   // hist threads
#define SB_T 512                   // scatter threads
#define SREC_CAP 8192              // LDS record stage per block (64 KB)
#define PT   512                   // phase block threads

static constexpr double PK  = 68719476736.0;   // 2^36
static constexpr double PKI = 1.0 / 68719476736.0;

// ---------------- binned path ----------------

__global__ __launch_bounds__(HT) void k_hist(
    const int* __restrict__ dstA, int* __restrict__ bhist,
    int E, int K, int span)
{
    __shared__ int lh[KMAX];
    for (int i = threadIdx.x; i < K; i += HT) lh[i] = 0;
    __syncthreads();
    const int beg = blockIdx.x * span;           // span % 4 == 0
    const int end = min(beg + span, E);          // E % 4 == 0
    for (int e = beg + (int)threadIdx.x * 4; e < end; e += HT * 4) {
        vi4 d = __builtin_nontemporal_load((const vi4*)&dstA[e]);
        atomicAdd(&lh[d.x >> K_BSH], 1);
        atomicAdd(&lh[d.y >> K_BSH], 1);
        atomicAdd(&lh[d.z >> K_BSH], 1);
        atomicAdd(&lh[d.w >> K_BSH], 1);
    }
    __syncthreads();
    int* row = bhist + (size_t)blockIdx.x * KMAX;
    for (int i = threadIdx.x; i < K; i += HT) row[i] = lh[i];
}

// One block per bucket k: exclusive prefix over the SB=1024 block rows
// (in place), total -> counts[k]. 64 threads x 16 rows each.
__global__ __launch_bounds__(64) void k_scanA(
    int* __restrict__ bhist, int* __restrict__ counts)
{
    const int k = blockIdx.x;
    const int t = threadIdx.x;                  // 0..63
    int v[16];
    int sum = 0;
    #pragma unroll
    for (int j = 0; j < 16; ++j) {
        v[j] = bhist[(size_t)(t * 16 + j) * KMAX + k];
        sum += v[j];
    }
    int incl = sum;
    #pragma unroll
    for (int d = 1; d < 64; d <<= 1) {
        int o = __shfl_up(incl, d, 64);
        if (t >= d) incl += o;
    }
    int excl = incl - sum;
    #pragma unroll
    for (int j = 0; j < 16; ++j) {
        const int tmp = v[j];
        bhist[(size_t)(t * 16 + j) * KMAX + k] = excl;
        excl += tmp;
    }
    if (t == 63) counts[k] = incl;
}

__global__ __launch_bounds__(KMAX) void k_scanB(
    const int* __restrict__ counts, int* __restrict__ offsets, int K)
{
    __shared__ int s[KMAX];
    const int t = threadIdx.x;
    const int v = (t < K) ? counts[t] : 0;
    s[t] = v;
    __syncthreads();
    for (int d = 1; d < KMAX; d <<= 1) {
        int add = (t >= d) ? s[t - d] : 0;
        __syncthreads();
        s[t] += add;
        __syncthreads();
    }
    if (t < K) {
        offsets[t] = s[t] - v;
        if (t == K - 1) offsets[K] = s[t];
    }
}

// LDS-staged scatter, single sweep: local histogram reconstructed from the
// scanned prefix table (no sweep A), records binned bucket-contiguous in
// LDS, flushed as dense per-bucket runs (full-line writes).
__global__ __launch_bounds__(SB_T) void k_scatter(
    const int* __restrict__ srcA, const int* __restrict__ dstA,
    const float* __restrict__ attr,
    const int* __restrict__ colbase,   // [SB][KMAX] excl prefixes (scanned)
    const int* __restrict__ counts,
    const int* __restrict__ offsets,
    int2* __restrict__ ebuf,
    int E, int K, int span)
{
    __shared__ int2 srec[SREC_CAP];            // 64 KB record stage
    __shared__ int  lpre[KMAX];                // local excl prefix (from hist)
    __shared__ int  lcnt[KMAX];
    __shared__ int  lbase[KMAX];               // global base per bucket
    __shared__ int  wsum[8];

    const int tid  = threadIdx.x;
    const int lane = tid & 63;
    const int wid  = tid >> 6;                 // 8 waves
    const int b    = blockIdx.x;
    const bool last = (b == (int)gridDim.x - 1);
    const int* row  = colbase + (size_t)b * KMAX;
    const int* rowN = row + KMAX;              // valid when !last

    // load own hist h[k] = nextPrefix - ownPrefix (last block: counts - own)
    for (int i = tid; i < KMAX; i += SB_T) {
        int h = 0, own = 0;
        if (i < K) {
            own = row[i];
            h   = (last ? counts[i] : rowN[i]) - own;
        }
        lpre[i]  = h;                          // temporarily holds hist
        lcnt[i]  = 0;
        lbase[i] = (i < K ? offsets[i] : 0) + own;
    }
    __syncthreads();

    // in-block exclusive scan of lpre[1024] (in place). 512 thr x 2 cells.
    {
        const int a0 = lpre[2 * tid], a1 = lpre[2 * tid + 1];
        int psum = a0 + a1;
        int incl = psum;
        #pragma unroll
        for (int d = 1; d < 64; d <<= 1) {
            int o = __shfl_up(incl, d, 64);
            if (lane >= d) incl += o;
        }
        if (lane == 63) wsum[wid] = incl;
        __syncthreads();
        if (tid == 0) {
            int run = 0;
            #pragma unroll
            for (int w = 0; w < 8; ++w) { int t2 = wsum[w]; wsum[w] = run; run += t2; }
        }
        __syncthreads();
        const int excl = wsum[wid] + incl - psum;
        lpre[2 * tid]     = excl;
        lpre[2 * tid + 1] = excl + a0;
    }
    __syncthreads();

    const int beg = b * span;
    const int end = min(beg + span, E);

    // single sweep: read streams, encode, place into LDS slot
    for (int e = beg + tid * 4; e < end; e += SB_T * 4) {
        vi4 s4 = __builtin_nontemporal_load((const vi4*)&srcA[e]);
        vi4 d4 = __builtin_nontemporal_load((const vi4*)&dstA[e]);
        vf4 a0 = __builtin_nontemporal_load((const vf4*)&attr[2 * e]);
        vf4 a1 = __builtin_nontemporal_load((const vf4*)&attr[2 * e + 4]);

        #define PLACE(SRC, DST, AX, AY)                                        \
        {                                                                      \
            const int k    = (DST) >> K_BSH;                                   \
            const int r    = atomicAdd(&lcnt[k], 1);                           \
            const int slot = lpre[k] + r;                                      \
            const int comp = ((AX) != 0.0f) ? 0 : 1;                           \
            const float av = comp ? (AY) : (AX);                               \
            unsigned enc = 0u;                                                 \
            if ((AX) != 0.0f || (AY) != 0.0f)                                  \
                enc = (__float_as_uint(av) & ~1u) | (unsigned)comp;            \
            const int w0 = (SRC) | (((DST) & (BUCKET - 1)) << 20);             \
            srec[slot] = make_int2(w0, (int)enc);                              \
        }
        PLACE(s4.x, d4.x, a0.x, a0.y)
        PLACE(s4.y, d4.y, a0.z, a0.w)
        PLACE(s4.z, d4.z, a1.x, a1.y)
        PLACE(s4.w, d4.w, a1.z, a1.w)
        #undef PLACE
    }
    __syncthreads();

    // flush: wave w owns buckets [w*128, w*128+128); dense coalesced stores
    const int kbeg = wid * (KMAX / 8);
    for (int k = kbeg; k < kbeg + (KMAX / 8); ++k) {
        const int cnt = lcnt[k];
        if (cnt == 0) continue;
        const int lp = lpre[k];
        const int gb = lbase[k];
        for (int i = lane; i < cnt; i += 64)
            ebuf[gb + i] = srec[lp + i];
    }
}

__global__ __launch_bounds__(PT) void k_phase1(
    const int2* __restrict__ ebuf, const int* __restrict__ offsets,
    const float* __restrict__ x, const float* __restrict__ a_x,
    float2* __restrict__ tmp2, float2* __restrict__ inv2, int N)
{
    __shared__ double pk0[BUCKET], pk1[BUCKET];   // sum + 2^36*cnt packed
    __shared__ float xl[BUCKET];
    const int k  = blockIdx.x;
    const int lo = k << K_BSH;
    for (int i = threadIdx.x; i < BUCKET; i += PT) {
        pk0[i] = 0.0; pk1[i] = 0.0;
        const int node = lo + i;
        xl[i] = (node < N) ? x[node] : 0.0f;
    }
    __syncthreads();
    const int beg = offsets[k], end = offsets[k + 1];
    const int start = beg & ~1;                   // 16B-aligned vi4 loads

    #define P1REC(W0, W1)                                                      \
    {                                                                          \
        const unsigned enc = (unsigned)(W1);                                   \
        if (enc != 0u) {                                                       \
            const int src  = (W0) & 0xFFFFF;                                   \
            const int dlo  = ((unsigned)(W0)) >> 20;                           \
            const float a  = __uint_as_float(enc);                             \
            const float msg = (x[src] - xl[dlo]) / a;                          \
            double* p = (enc & 1) ? pk1 : pk0;                                 \
            atomicAdd(&p[dlo], (double)msg + PK);                              \
        }                                                                      \
    }
    // 4 records / thread / iter (2x vi4) for gather MLP
    for (int i = start + (int)threadIdx.x * 4; i < end; i += PT * 4) {
        vi4 r0 = __builtin_nontemporal_load((const vi4*)(ebuf + i));
        if (i + 2 < end) {
            vi4 r1 = __builtin_nontemporal_load((const vi4*)(ebuf + i + 2));
            if (i >= beg)    P1REC(r0.x, r0.y)
            if (i + 1 < end) P1REC(r0.z, r0.w)
            P1REC(r1.x, r1.y)
            if (i + 3 < end) P1REC(r1.z, r1.w)
        } else {
            if (i >= beg)    P1REC(r0.x, r0.y)
            if (i + 1 < end) P1REC(r0.z, r0.w)
        }
    }
    #undef P1REC

    __syncthreads();
    for (int i = threadIdx.x; i < BUCKET; i += PT) {
        const int node = lo + i;
        if (node >= N) break;
        const double p0 = pk0[i], p1 = pk1[i];
        const double c0 = rint(p0 * PKI);
        const double c1 = rint(p1 * PKI);
        const float  s0 = (float)(p0 - c0 * PK);
        const float  s1 = (float)(p1 - c1 * PK);
        const float  i0 = 1.0f / (float)fmax(c0, 1.0);
        const float  i1 = 1.0f / (float)fmax(c1, 1.0);
        const float  a  = a_x[node];
        float2 t; t.x = a * s0 * i0; t.y = a * s1 * i1;
        float2 v; v.x = i0; v.y = i1;
        tmp2[node] = t;
        inv2[node] = v;
    }
}

__global__ __launch_bounds__(PT) void k_phase2(
    const int2* __restrict__ ebuf, const int* __restrict__ offsets,
    const float2* __restrict__ tmp2, const float2* __restrict__ inv2,
    const int* __restrict__ mask,
    float* __restrict__ out, int N)
{
    __shared__ float acc[BUCKET];
    __shared__ float2 tl[BUCKET], il[BUCKET];
    const int k  = blockIdx.x;
    const int lo = k << K_BSH;
    for (int i = threadIdx.x; i < BUCKET; i += PT) {
        acc[i] = 0.0f;
        const int node = lo + i;
        if (node < N) { tl[i] = tmp2[node]; il[i] = inv2[node]; }
        else          { tl[i] = make_float2(0.f, 0.f); il[i] = make_float2(0.f, 0.f); }
    }
    __syncthreads();
    const int beg = offsets[k], end = offsets[k + 1];
    const int start = beg & ~1;

    #define P2REC(W0, W1)                                                      \
    {                                                                          \
        const unsigned enc = (unsigned)(W1);                                   \
        if (enc != 0u) {                                                       \
            const int src  = (W0) & 0xFFFFF;                                   \
            const int dlo  = ((unsigned)(W0)) >> 20;                           \
            const int comp = enc & 1;                                          \
            const float a  = __uint_as_float(enc);                             \
            const float2 ts = tmp2[src];                                       \
            const float2 td = tl[dlo];                                         \
            const float2 ic = il[dlo];                                         \
            const float tsv = comp ? ts.y : ts.x;                              \
            const float tdv = comp ? td.y : td.x;                              \
            const float icv = comp ? ic.y : ic.x;                              \
            atomicAdd(&acc[dlo], (tsv - tdv) / a * icv);                       \
        }                                                                      \
    }
    for (int i = start + (int)threadIdx.x * 4; i < end; i += PT * 4) {
        vi4 r0 = __builtin_nontemporal_load((const vi4*)(ebuf + i));
        if (i + 2 < end) {
            vi4 r1 = __builtin_nontemporal_load((const vi4*)(ebuf + i + 2));
            if (i >= beg)    P2REC(r0.x, r0.y)
            if (i + 1 < end) P2REC(r0.z, r0.w)
            P2REC(r1.x, r1.y)
            if (i + 3 < end) P2REC(r1.z, r1.w)
        } else {
            if (i >= beg)    P2REC(r0.x, r0.y)
            if (i + 1 < end) P2REC(r0.z, r0.w)
        }
    }
    #undef P2REC

    __syncthreads();
    for (int i = threadIdx.x; i < BUCKET; i += PT) {
        const int node = lo + i;
        if (node >= N) break;
        out[node] = (acc[i] + 1.0f) * (1.0f - (float)mask[node]);
    }
}

// ---------------- fallback path (proven R5, 1042 us) ----------------

#define BLK   256
#define EPT   4
#define CHUNK (BLK * EPT)
#define GRAB  8

__device__ __forceinline__ int xcd_id() {
    return __builtin_amdgcn_s_getreg((31u << 11) | 20) & 7;
}
__device__ __forceinline__ void wg_add_d(double* p, double v) {
    __hip_atomic_fetch_add(p, v, __ATOMIC_RELAXED, __HIP_MEMORY_SCOPE_WORKGROUP);
}
__device__ __forceinline__ void wg_add_f(float* p, float v) {
    __hip_atomic_fetch_add(p, v, __ATOMIC_RELAXED, __HIP_MEMORY_SCOPE_WORKGROUP);
}

__global__ __launch_bounds__(BLK) void edge_pass1(
    const int* __restrict__ srcA, const int* __restrict__ dstA,
    const float* __restrict__ attr, const float* __restrict__ x,
    double2* __restrict__ pk, int* __restrict__ tickets,
    int E, int nchunk, int sliceSz, int N)
{
    const int xcc = xcd_id();
    const int lo  = xcc * sliceSz;
    const int w   = min(sliceSz, N - lo);
    __shared__ int s_q;
    for (;;) {
        if (threadIdx.x == 0) s_q = atomicAdd(&tickets[xcc], 1);
        __syncthreads();
        const int q = s_q;
        __syncthreads();
        if (q * GRAB >= nchunk) break;
        for (int cc = 0; cc < GRAB; ++cc) {
            const int c = q * GRAB + cc;
            if (c >= nchunk) break;
            const int base = c * CHUNK + threadIdx.x * EPT;
            if (base >= E) continue;
            vi4 sv  = __builtin_nontemporal_load((const vi4*)&srcA[base]);
            vi4 dv  = __builtin_nontemporal_load((const vi4*)&dstA[base]);
            vf4 a01 = __builtin_nontemporal_load((const vf4*)&attr[2 * base]);
            vf4 a23 = __builtin_nontemporal_load((const vf4*)&attr[2 * base + 4]);
            #define P1(S, D, AX, AY)                                                  \
                if ((unsigned)((D) - lo) < (unsigned)w) {                             \
                    float diff = x[S] - x[D];                                         \
                    if ((AX) != 0.0f) wg_add_d(&pk[D].x, (double)(diff/(AX)) + PK);   \
                    if ((AY) != 0.0f) wg_add_d(&pk[D].y, (double)(diff/(AY)) + PK);   \
                }
            P1(sv.x, dv.x, a01.x, a01.y)
            P1(sv.y, dv.y, a01.z, a01.w)
            P1(sv.z, dv.z, a23.x, a23.y)
            P1(sv.w, dv.w, a23.z, a23.w)
            #undef P1
        }
    }
}

__global__ __launch_bounds__(BLK) void node_mid(
    double2* __restrict__ pk, const float* __restrict__ a_x, int N)
{
    float4* f4 = (float4*)pk;
    for (int i = blockIdx.x * BLK + threadIdx.x; i < N; i += gridDim.x * BLK) {
        double2 p = pk[i];
        double c0 = rint(p.x * PKI);
        double c1 = rint(p.y * PKI);
        float  s0 = (float)(p.x - c0 * PK);
        float  s1 = (float)(p.y - c1 * PK);
        float  i0 = 1.0f / (float)fmax(c0, 1.0);
        float  i1 = 1.0f / (float)fmax(c1, 1.0);
        float  a  = a_x[i];
        f4[i] = make_float4(a * s0 * i0, a * s1 * i1, i0, i1);
    }
}

__global__ __launch_bounds__(BLK) void edge_pass2(
    const int* __restrict__ srcA, const int* __restrict__ dstA,
    const float* __restrict__ attr, const float4* __restrict__ tf,
    float* __restrict__ acc2, int* __restrict__ tickets,
    int E, int nchunk, int sliceSz, int N)
{
    const int xcc = xcd_id();
    const int lo  = xcc * sliceSz;
    const int w   = min(sliceSz, N - lo);
    __shared__ int s_q;
    for (;;) {
        if (threadIdx.x == 0) s_q = atomicAdd(&tickets[8 + xcc], 1);
        __syncthreads();
        const int q = s_q;
        __syncthreads();
        if (q * GRAB >= nchunk) break;
        for (int cc = 0; cc < GRAB; ++cc) {
            const int c = q * GRAB + cc;
            if (c >= nchunk) break;
            const int base = c * CHUNK + threadIdx.x * EPT;
            if (base >= E) continue;
            vi4 sv  = __builtin_nontemporal_load((const vi4*)&srcA[base]);
            vi4 dv  = __builtin_nontemporal_load((const vi4*)&dstA[base]);
            vf4 a01 = __builtin_nontemporal_load((const vf4*)&attr[2 * base]);
            vf4 a23 = __builtin_nontemporal_load((const vf4*)&attr[2 * base + 4]);
            #define P2(S, D, AX, AY)                                                  \
                if ((unsigned)((D) - lo) < (unsigned)w) {                             \
                    float4 ts = tf[S], td = tf[D];                                    \
                    float contrib = 0.0f; bool any = false;                           \
                    if ((AX) != 0.0f) { contrib += (ts.x - td.x) / (AX) * td.z; any = true; } \
                    if ((AY) != 0.0f) { contrib += (ts.y - td.y) / (AY) * td.w; any = true; } \
                    if (any) wg_add_f(&acc2[D], contrib);                             \
                }
            P2(sv.x, dv.x, a01.x, a01.y)
            P2(sv.y, dv.y, a01.z, a01.w)
            P2(sv.z, dv.z, a23.x, a23.y)
            P2(sv.w, dv.w, a23.z, a23.w)
            #undef P2
        }
    }
}

__global__ __launch_bounds__(BLK) void node_out(
    const float* __restrict__ acc2, const int* __restrict__ mask,
    float* __restrict__ out, int N)
{
    for (int i = blockIdx.x * BLK + threadIdx.x; i < N; i += gridDim.x * BLK)
        out[i] = (acc2[i] + 1.0f) * (1.0f - (float)mask[i]);
}

// ---------------- launcher ----------------

extern "C" void kernel_launch(void* const* d_in, const int* in_sizes, int n_in,
                              void* d_out, int out_size, void* d_ws, size_t ws_size,
                              hipStream_t stream)
{
    const float* x    = (const float*)d_in[0];
    const float* a_x  = (const float*)d_in[1];
    const int*   eidx = (const int*)d_in[2];
    const float* attr = (const float*)d_in[3];
    const int*   mask = (const int*)d_in[4];
    float* out = (float*)d_out;

    const int N = in_sizes[0];
    const int E = in_sizes[2] / 2;
    const int K = (N + BUCKET - 1) >> K_BSH;

    const size_t need = (size_t)E * 8 + (size_t)N * 16 + 16384;
    const size_t bhist_bytes = (size_t)SB * KMAX * 4;   // 4 MB
    const int span = (((E + SB - 1) / SB) + 3) & ~3;

    if (ws_size >= need && N <= (1 << 20) && K <= KMAX &&
        bhist_bytes <= (size_t)N * 8 && span <= SREC_CAP) {
        char* p = (char*)d_ws;
        int2*   ebuf    = (int2*)p;
        float2* tmp2    = (float2*)(p + (size_t)E * 8);
        float2* inv2    = (float2*)(p + (size_t)E * 8 + (size_t)N * 8);
        int*    counts  = (int*)(p + (size_t)E * 8 + (size_t)N * 16);
        int*    offsets = counts + KMAX;          // K+1 slots
        int*    bhist   = (int*)tmp2;             // aliased: dead until phase1

        const int* srcA = eidx;
        const int* dstA = eidx + E;

        k_hist<<<SB, HT, 0, stream>>>(dstA, bhist, E, K, span);
        k_scanA<<<K, 64, 0, stream>>>(bhist, counts);
        k_scanB<<<1, KMAX, 0, stream>>>(counts, offsets, K);
        k_scatter<<<SB, SB_T, 0, stream>>>(srcA, dstA, attr, bhist, counts,
                                           offsets, ebuf, E, K, span);
        k_phase1<<<K, PT, 0, stream>>>(ebuf, offsets, x, a_x, tmp2, inv2, N);
        k_phase2<<<K, PT, 0, stream>>>(ebuf, offsets, tmp2, inv2, mask, out, N);
    } else {
        // proven R5 fallback (20N+64 bytes of ws)
        char* ws = (char*)d_ws;
        double2* pk      = (double2*)(ws);
        float*   acc2    = (float*)(ws + (size_t)16 * N);
        int*     tickets = (int*)(ws + (size_t)20 * N);

        hipMemsetAsync(d_ws, 0, (size_t)20 * N + 64, stream);

        const int sliceSz = (N + 7) / 8;
        const int nchunk  = (E + CHUNK - 1) / CHUNK;
        const int EGRID   = 2048;
        int ngrid = (N + BLK - 1) / BLK;
        const int NGRID   = ngrid < 2048 ? ngrid : 2048;

        edge_pass1<<<EGRID, BLK, 0, stream>>>(
            eidx, eidx + E, attr, x, pk, tickets, E, nchunk, sliceSz, N);
        node_mid<<<NGRID, BLK, 0, stream>>>(pk, a_x, N);
        edge_pass2<<<EGRID, BLK, 0, stream>>>(
            eidx, eidx + E, attr, (const float4*)pk, acc2, tickets,
            E, nchunk, sliceSz, N);
        node_out<<<NGRID, BLK, 0, stream>>>(acc2, mask, out, N);
    }
}

// Round 13
// 333.304 us; speedup vs baseline: 3.9176x; 1.0974x over previous
//
#include <hip/hip_runtime.h>

// Darcy flow graph PDE residual — bucket-binned LDS aggregation, rev 7.
//
// Measured history: global float atomics ~17-20 G/s (R1/R2/R5); write
// amplification on scattered stores fixed via LDS write-combining (R11);
// R12: k_phase2 87 us, FETCH 300 MB vs 72 MB compulsory -> random 8 B
// gathers from 16 MB tmp2/inv2 miss the 4 MB per-XCD L2, each miss pulls a
// 64 B line over the fabric. Rev 7: compress gathered node arrays to bf16 —
// tpk[N] = {bf16 tmp0, bf16 tmp1} in one uint (4 MB = L2-resident),
// xpk[N] = bf16 x (2 MB) packed inside k_hist. Tolerance is 7.7e9; bf16
// error ~0.4% rel is orders below it.
//
// Edge record (8 B): w0 = src | dlo<<20 (dlo 10 bits); w1 = attr bits with
// LSB overwritten by comp (0=x,1=y); w1==0 => invalid edge.
//
// Binned ws layout (8E + 14N + 16KB ~= 78 MB < 80 MB proven):
//   [0, 8E)             ebuf : int2[E]
//   [8E, 8E+4N)         tpk  : uint[N]    packed bf16 {tmp0,tmp1}
//   [8E+4N, 8E+12N)     inv2 : float2[N]  (first 4 MB aliased as bhist)
//   [8E+12N, 8E+14N)    xpk  : ushort[N]  packed bf16 x
//   [8E+14N, +16KB)     counts[KMAX] | offsets[KMAX+1]
// Fallback (ws too small): proven R5 atomic path (1042 us).

typedef int   vi2 __attribute__((ext_vector_type(2)));
typedef int   vi4 __attribute__((ext_vector_type(4)));
typedef float vf4 __attribute__((ext_vector_type(4)));

#define K_BSH  10
#define BUCKET (1 << K_BSH)        // 1024 nodes per bucket
#define KMAX   1024

#define SB   1024                  // scatter/hist blocks
#define HT   512                   // hist threads
#define SB_T 512                   // scatter threads
#define SREC_CAP 8192              // LDS record stage per block (64 KB)
#define PT   512                   // phase block threads

static constexpr double PK  = 68719476736.0;   // 2^36
static constexpr double PKI = 1.0 / 68719476736.0;

__device__ __forceinline__ unsigned pack_bf16x2(float a, float b) {
    const unsigned ua = (__float_as_uint(a) + 0x8000u) >> 16;
    const unsigned ub = (__float_as_uint(b) + 0x8000u) & 0xFFFF0000u;
    return ua | ub;
}
__device__ __forceinline__ float bf_lo(unsigned p) {
    return __uint_as_float(p << 16);
}
__device__ __forceinline__ float bf_hi(unsigned p) {
    return __uint_as_float(p & 0xFFFF0000u);
}

// ---------------- binned path ----------------

__global__ __launch_bounds__(HT) void k_hist(
    const int* __restrict__ dstA, const float* __restrict__ x,
    int* __restrict__ bhist, unsigned short* __restrict__ xpk,
    int E, int K, int span, int N)
{
    __shared__ int lh[KMAX];
    for (int i = threadIdx.x; i < K; i += HT) lh[i] = 0;
    __syncthreads();
    const int beg = blockIdx.x * span;           // span % 4 == 0
    const int end = min(beg + span, E);          // E % 4 == 0
    for (int e = beg + (int)threadIdx.x * 4; e < end; e += HT * 4) {
        vi4 d = __builtin_nontemporal_load((const vi4*)&dstA[e]);
        atomicAdd(&lh[d.x >> K_BSH], 1);
        atomicAdd(&lh[d.y >> K_BSH], 1);
        atomicAdd(&lh[d.z >> K_BSH], 1);
        atomicAdd(&lh[d.w >> K_BSH], 1);
    }
    // pack x -> bf16 (grid-stride; independent of hist loop)
    for (int i = blockIdx.x * HT + threadIdx.x; i < N; i += SB * HT)
        xpk[i] = (unsigned short)((__float_as_uint(x[i]) + 0x8000u) >> 16);
    __syncthreads();
    int* row = bhist + (size_t)blockIdx.x * KMAX;
    for (int i = threadIdx.x; i < K; i += HT) row[i] = lh[i];
}

// One block per bucket k: exclusive prefix over the SB=1024 block rows
// (in place), total -> counts[k]. 64 threads x 16 rows each.
__global__ __launch_bounds__(64) void k_scanA(
    int* __restrict__ bhist, int* __restrict__ counts)
{
    const int k = blockIdx.x;
    const int t = threadIdx.x;                  // 0..63
    int v[16];
    int sum = 0;
    #pragma unroll
    for (int j = 0; j < 16; ++j) {
        v[j] = bhist[(size_t)(t * 16 + j) * KMAX + k];
        sum += v[j];
    }
    int incl = sum;
    #pragma unroll
    for (int d = 1; d < 64; d <<= 1) {
        int o = __shfl_up(incl, d, 64);
        if (t >= d) incl += o;
    }
    int excl = incl - sum;
    #pragma unroll
    for (int j = 0; j < 16; ++j) {
        const int tmp = v[j];
        bhist[(size_t)(t * 16 + j) * KMAX + k] = excl;
        excl += tmp;
    }
    if (t == 63) counts[k] = incl;
}

__global__ __launch_bounds__(KMAX) void k_scanB(
    const int* __restrict__ counts, int* __restrict__ offsets, int K)
{
    __shared__ int s[KMAX];
    const int t = threadIdx.x;
    const int v = (t < K) ? counts[t] : 0;
    s[t] = v;
    __syncthreads();
    for (int d = 1; d < KMAX; d <<= 1) {
        int add = (t >= d) ? s[t - d] : 0;
        __syncthreads();
        s[t] += add;
        __syncthreads();
    }
    if (t < K) {
        offsets[t] = s[t] - v;
        if (t == K - 1) offsets[K] = s[t];
    }
}

// LDS-staged scatter, single sweep: local histogram reconstructed from the
// scanned prefix table, records binned bucket-contiguous in LDS, flushed
// as dense per-bucket runs (full-line writes).
__global__ __launch_bounds__(SB_T) void k_scatter(
    const int* __restrict__ srcA, const int* __restrict__ dstA,
    const float* __restrict__ attr,
    const int* __restrict__ colbase,   // [SB][KMAX] excl prefixes (scanned)
    const int* __restrict__ counts,
    const int* __restrict__ offsets,
    int2* __restrict__ ebuf,
    int E, int K, int span)
{
    __shared__ int2 srec[SREC_CAP];            // 64 KB record stage
    __shared__ int  lpre[KMAX];
    __shared__ int  lcnt[KMAX];
    __shared__ int  lbase[KMAX];
    __shared__ int  wsum[8];

    const int tid  = threadIdx.x;
    const int lane = tid & 63;
    const int wid  = tid >> 6;                 // 8 waves
    const int b    = blockIdx.x;
    const bool last = (b == (int)gridDim.x - 1);
    const int* row  = colbase + (size_t)b * KMAX;
    const int* rowN = row + KMAX;

    for (int i = tid; i < KMAX; i += SB_T) {
        int h = 0, own = 0;
        if (i < K) {
            own = row[i];
            h   = (last ? counts[i] : rowN[i]) - own;
        }
        lpre[i]  = h;
        lcnt[i]  = 0;
        lbase[i] = (i < K ? offsets[i] : 0) + own;
    }
    __syncthreads();

    {
        const int a0 = lpre[2 * tid], a1 = lpre[2 * tid + 1];
        int psum = a0 + a1;
        int incl = psum;
        #pragma unroll
        for (int d = 1; d < 64; d <<= 1) {
            int o = __shfl_up(incl, d, 64);
            if (lane >= d) incl += o;
        }
        if (lane == 63) wsum[wid] = incl;
        __syncthreads();
        if (tid == 0) {
            int run = 0;
            #pragma unroll
            for (int w = 0; w < 8; ++w) { int t2 = wsum[w]; wsum[w] = run; run += t2; }
        }
        __syncthreads();
        const int excl = wsum[wid] + incl - psum;
        lpre[2 * tid]     = excl;
        lpre[2 * tid + 1] = excl + a0;
    }
    __syncthreads();

    const int beg = b * span;
    const int end = min(beg + span, E);

    for (int e = beg + tid * 4; e < end; e += SB_T * 4) {
        vi4 s4 = __builtin_nontemporal_load((const vi4*)&srcA[e]);
        vi4 d4 = __builtin_nontemporal_load((const vi4*)&dstA[e]);
        vf4 a0 = __builtin_nontemporal_load((const vf4*)&attr[2 * e]);
        vf4 a1 = __builtin_nontemporal_load((const vf4*)&attr[2 * e + 4]);

        #define PLACE(SRC, DST, AX, AY)                                        \
        {                                                                      \
            const int k    = (DST) >> K_BSH;                                   \
            const int r    = atomicAdd(&lcnt[k], 1);                           \
            const int slot = lpre[k] + r;                                      \
            const int comp = ((AX) != 0.0f) ? 0 : 1;                           \
            const float av = comp ? (AY) : (AX);                               \
            unsigned enc = 0u;                                                 \
            if ((AX) != 0.0f || (AY) != 0.0f)                                  \
                enc = (__float_as_uint(av) & ~1u) | (unsigned)comp;            \
            const int w0 = (SRC) | (((DST) & (BUCKET - 1)) << 20);             \
            srec[slot] = make_int2(w0, (int)enc);                              \
        }
        PLACE(s4.x, d4.x, a0.x, a0.y)
        PLACE(s4.y, d4.y, a0.z, a0.w)
        PLACE(s4.z, d4.z, a1.x, a1.y)
        PLACE(s4.w, d4.w, a1.z, a1.w)
        #undef PLACE
    }
    __syncthreads();

    const int kbeg = wid * (KMAX / 8);
    for (int k = kbeg; k < kbeg + (KMAX / 8); ++k) {
        const int cnt = lcnt[k];
        if (cnt == 0) continue;
        const int lp = lpre[k];
        const int gb = lbase[k];
        for (int i = lane; i < cnt; i += 64)
            ebuf[gb + i] = srec[lp + i];
    }
}

__global__ __launch_bounds__(PT) void k_phase1(
    const int2* __restrict__ ebuf, const int* __restrict__ offsets,
    const unsigned short* __restrict__ xpk,     // bf16 x (src gathers, 2 MB)
    const float* __restrict__ x,                // full x (dst preload)
    const float* __restrict__ a_x,
    unsigned* __restrict__ tpk,                 // out: packed bf16 {tmp0,tmp1}
    float2* __restrict__ inv2, int N)
{
    __shared__ double pk0[BUCKET], pk1[BUCKET];   // sum + 2^36*cnt packed
    __shared__ float xl[BUCKET];
    const int k  = blockIdx.x;
    const int lo = k << K_BSH;
    for (int i = threadIdx.x; i < BUCKET; i += PT) {
        pk0[i] = 0.0; pk1[i] = 0.0;
        const int node = lo + i;
        xl[i] = (node < N) ? x[node] : 0.0f;
    }
    __syncthreads();
    const int beg = offsets[k], end = offsets[k + 1];
    const int start = beg & ~1;                   // 16B-aligned vi4 loads

    #define P1REC(W0, W1)                                                      \
    {                                                                          \
        const unsigned enc = (unsigned)(W1);                                   \
        if (enc != 0u) {                                                       \
            const int src  = (W0) & 0xFFFFF;                                   \
            const int dlo  = ((unsigned)(W0)) >> 20;                           \
            const float a  = __uint_as_float(enc);                             \
            const float xs = __uint_as_float((unsigned)xpk[src] << 16);        \
            const float msg = (xs - xl[dlo]) / a;                              \
            double* p = (enc & 1) ? pk1 : pk0;                                 \
            atomicAdd(&p[dlo], (double)msg + PK);                              \
        }                                                                      \
    }
    for (int i = start + (int)threadIdx.x * 4; i < end; i += PT * 4) {
        vi4 r0 = __builtin_nontemporal_load((const vi4*)(ebuf + i));
        if (i + 2 < end) {
            vi4 r1 = __builtin_nontemporal_load((const vi4*)(ebuf + i + 2));
            if (i >= beg)    P1REC(r0.x, r0.y)
            if (i + 1 < end) P1REC(r0.z, r0.w)
            P1REC(r1.x, r1.y)
            if (i + 3 < end) P1REC(r1.z, r1.w)
        } else {
            if (i >= beg)    P1REC(r0.x, r0.y)
            if (i + 1 < end) P1REC(r0.z, r0.w)
        }
    }
    #undef P1REC

    __syncthreads();
    for (int i = threadIdx.x; i < BUCKET; i += PT) {
        const int node = lo + i;
        if (node >= N) break;
        const double p0 = pk0[i], p1 = pk1[i];
        const double c0 = rint(p0 * PKI);
        const double c1 = rint(p1 * PKI);
        const float  s0 = (float)(p0 - c0 * PK);
        const float  s1 = (float)(p1 - c1 * PK);
        const float  i0 = 1.0f / (float)fmax(c0, 1.0);
        const float  i1 = 1.0f / (float)fmax(c1, 1.0);
        const float  a  = a_x[node];
        tpk[node] = pack_bf16x2(a * s0 * i0, a * s1 * i1);
        float2 v; v.x = i0; v.y = i1;
        inv2[node] = v;
    }
}

__global__ __launch_bounds__(PT) void k_phase2(
    const int2* __restrict__ ebuf, const int* __restrict__ offsets,
    const unsigned* __restrict__ tpk,           // packed bf16 {tmp0,tmp1}, 4 MB
    const float2* __restrict__ inv2,
    const int* __restrict__ mask,
    float* __restrict__ out, int N)
{
    __shared__ float acc[BUCKET];
    __shared__ float2 tl[BUCKET], il[BUCKET];
    const int k  = blockIdx.x;
    const int lo = k << K_BSH;
    for (int i = threadIdx.x; i < BUCKET; i += PT) {
        acc[i] = 0.0f;
        const int node = lo + i;
        if (node < N) {
            const unsigned p = tpk[node];
            tl[i] = make_float2(bf_lo(p), bf_hi(p));
            il[i] = inv2[node];
        } else {
            tl[i] = make_float2(0.f, 0.f); il[i] = make_float2(0.f, 0.f);
        }
    }
    __syncthreads();
    const int beg = offsets[k], end = offsets[k + 1];
    const int start = beg & ~1;

    #define P2REC(W0, W1)                                                      \
    {                                                                          \
        const unsigned enc = (unsigned)(W1);                                   \
        if (enc != 0u) {                                                       \
            const int src  = (W0) & 0xFFFFF;                                   \
            const int dlo  = ((unsigned)(W0)) >> 20;                           \
            const int comp = enc & 1;                                          \
            const float a  = __uint_as_float(enc);                             \
            const unsigned ps = tpk[src];                                      \
            const float2 td = tl[dlo];                                         \
            const float2 ic = il[dlo];                                         \
            const float tsv = comp ? bf_hi(ps) : bf_lo(ps);                    \
            const float tdv = comp ? td.y : td.x;                              \
            const float icv = comp ? ic.y : ic.x;                              \
            atomicAdd(&acc[dlo], (tsv - tdv) / a * icv);                       \
        }                                                                      \
    }
    for (int i = start + (int)threadIdx.x * 4; i < end; i += PT * 4) {
        vi4 r0 = __builtin_nontemporal_load((const vi4*)(ebuf + i));
        if (i + 2 < end) {
            vi4 r1 = __builtin_nontemporal_load((const vi4*)(ebuf + i + 2));
            if (i >= beg)    P2REC(r0.x, r0.y)
            if (i + 1 < end) P2REC(r0.z, r0.w)
            P2REC(r1.x, r1.y)
            if (i + 3 < end) P2REC(r1.z, r1.w)
        } else {
            if (i >= beg)    P2REC(r0.x, r0.y)
            if (i + 1 < end) P2REC(r0.z, r0.w)
        }
    }
    #undef P2REC

    __syncthreads();
    for (int i = threadIdx.x; i < BUCKET; i += PT) {
        const int node = lo + i;
        if (node >= N) break;
        out[node] = (acc[i] + 1.0f) * (1.0f - (float)mask[node]);
    }
}

// ---------------- fallback path (proven R5, 1042 us) ----------------

#define BLK   256
#define EPT   4
#define CHUNK (BLK * EPT)
#define GRAB  8

__device__ __forceinline__ int xcd_id() {
    return __builtin_amdgcn_s_getreg((31u << 11) | 20) & 7;
}
__device__ __forceinline__ void wg_add_d(double* p, double v) {
    __hip_atomic_fetch_add(p, v, __ATOMIC_RELAXED, __HIP_MEMORY_SCOPE_WORKGROUP);
}
__device__ __forceinline__ void wg_add_f(float* p, float v) {
    __hip_atomic_fetch_add(p, v, __ATOMIC_RELAXED, __HIP_MEMORY_SCOPE_WORKGROUP);
}

__global__ __launch_bounds__(BLK) void edge_pass1(
    const int* __restrict__ srcA, const int* __restrict__ dstA,
    const float* __restrict__ attr, const float* __restrict__ x,
    double2* __restrict__ pk, int* __restrict__ tickets,
    int E, int nchunk, int sliceSz, int N)
{
    const int xcc = xcd_id();
    const int lo  = xcc * sliceSz;
    const int w   = min(sliceSz, N - lo);
    __shared__ int s_q;
    for (;;) {
        if (threadIdx.x == 0) s_q = atomicAdd(&tickets[xcc], 1);
        __syncthreads();
        const int q = s_q;
        __syncthreads();
        if (q * GRAB >= nchunk) break;
        for (int cc = 0; cc < GRAB; ++cc) {
            const int c = q * GRAB + cc;
            if (c >= nchunk) break;
            const int base = c * CHUNK + threadIdx.x * EPT;
            if (base >= E) continue;
            vi4 sv  = __builtin_nontemporal_load((const vi4*)&srcA[base]);
            vi4 dv  = __builtin_nontemporal_load((const vi4*)&dstA[base]);
            vf4 a01 = __builtin_nontemporal_load((const vf4*)&attr[2 * base]);
            vf4 a23 = __builtin_nontemporal_load((const vf4*)&attr[2 * base + 4]);
            #define P1(S, D, AX, AY)                                                  \
                if ((unsigned)((D) - lo) < (unsigned)w) {                             \
                    float diff = x[S] - x[D];                                         \
                    if ((AX) != 0.0f) wg_add_d(&pk[D].x, (double)(diff/(AX)) + PK);   \
                    if ((AY) != 0.0f) wg_add_d(&pk[D].y, (double)(diff/(AY)) + PK);   \
                }
            P1(sv.x, dv.x, a01.x, a01.y)
            P1(sv.y, dv.y, a01.z, a01.w)
            P1(sv.z, dv.z, a23.x, a23.y)
            P1(sv.w, dv.w, a23.z, a23.w)
            #undef P1
        }
    }
}

__global__ __launch_bounds__(BLK) void node_mid(
    double2* __restrict__ pk, const float* __restrict__ a_x, int N)
{
    float4* f4 = (float4*)pk;
    for (int i = blockIdx.x * BLK + threadIdx.x; i < N; i += gridDim.x * BLK) {
        double2 p = pk[i];
        double c0 = rint(p.x * PKI);
        double c1 = rint(p.y * PKI);
        float  s0 = (float)(p.x - c0 * PK);
        float  s1 = (float)(p.y - c1 * PK);
        float  i0 = 1.0f / (float)fmax(c0, 1.0);
        float  i1 = 1.0f / (float)fmax(c1, 1.0);
        float  a  = a_x[i];
        f4[i] = make_float4(a * s0 * i0, a * s1 * i1, i0, i1);
    }
}

__global__ __launch_bounds__(BLK) void edge_pass2(
    const int* __restrict__ srcA, const int* __restrict__ dstA,
    const float* __restrict__ attr, const float4* __restrict__ tf,
    float* __restrict__ acc2, int* __restrict__ tickets,
    int E, int nchunk, int sliceSz, int N)
{
    const int xcc = xcd_id();
    const int lo  = xcc * sliceSz;
    const int w   = min(sliceSz, N - lo);
    __shared__ int s_q;
    for (;;) {
        if (threadIdx.x == 0) s_q = atomicAdd(&tickets[8 + xcc], 1);
        __syncthreads();
        const int q = s_q;
        __syncthreads();
        if (q * GRAB >= nchunk) break;
        for (int cc = 0; cc < GRAB; ++cc) {
            const int c = q * GRAB + cc;
            if (c >= nchunk) break;
            const int base = c * CHUNK + threadIdx.x * EPT;
            if (base >= E) continue;
            vi4 sv  = __builtin_nontemporal_load((const vi4*)&srcA[base]);
            vi4 dv  = __builtin_nontemporal_load((const vi4*)&dstA[base]);
            vf4 a01 = __builtin_nontemporal_load((const vf4*)&attr[2 * base]);
            vf4 a23 = __builtin_nontemporal_load((const vf4*)&attr[2 * base + 4]);
            #define P2(S, D, AX, AY)                                                  \
                if ((unsigned)((D) - lo) < (unsigned)w) {                             \
                    float4 ts = tf[S], td = tf[D];                                    \
                    float contrib = 0.0f; bool any = false;                           \
                    if ((AX) != 0.0f) { contrib += (ts.x - td.x) / (AX) * td.z; any = true; } \
                    if ((AY) != 0.0f) { contrib += (ts.y - td.y) / (AY) * td.w; any = true; } \
                    if (any) wg_add_f(&acc2[D], contrib);                             \
                }
            P2(sv.x, dv.x, a01.x, a01.y)
            P2(sv.y, dv.y, a01.z, a01.w)
            P2(sv.z, dv.z, a23.x, a23.y)
            P2(sv.w, dv.w, a23.z, a23.w)
            #undef P2
        }
    }
}

__global__ __launch_bounds__(BLK) void node_out(
    const float* __restrict__ acc2, const int* __restrict__ mask,
    float* __restrict__ out, int N)
{
    for (int i = blockIdx.x * BLK + threadIdx.x; i < N; i += gridDim.x * BLK)
        out[i] = (acc2[i] + 1.0f) * (1.0f - (float)mask[i]);
}

// ---------------- launcher ----------------

extern "C" void kernel_launch(void* const* d_in, const int* in_sizes, int n_in,
                              void* d_out, int out_size, void* d_ws, size_t ws_size,
                              hipStream_t stream)
{
    const float* x    = (const float*)d_in[0];
    const float* a_x  = (const float*)d_in[1];
    const int*   eidx = (const int*)d_in[2];
    const float* attr = (const float*)d_in[3];
    const int*   mask = (const int*)d_in[4];
    float* out = (float*)d_out;

    const int N = in_sizes[0];
    const int E = in_sizes[2] / 2;
    const int K = (N + BUCKET - 1) >> K_BSH;

    const size_t need = (size_t)E * 8 + (size_t)N * 14 + 16384;
    const size_t bhist_bytes = (size_t)SB * KMAX * 4;   // 4 MB
    const int span = (((E + SB - 1) / SB) + 3) & ~3;

    if (ws_size >= need && N <= (1 << 20) && K <= KMAX &&
        bhist_bytes <= (size_t)N * 8 && span <= SREC_CAP) {
        char* p = (char*)d_ws;
        int2*     ebuf    = (int2*)p;
        unsigned* tpk     = (unsigned*)(p + (size_t)E * 8);
        float2*   inv2    = (float2*)(p + (size_t)E * 8 + (size_t)N * 4);
        unsigned short* xpk = (unsigned short*)(p + (size_t)E * 8 + (size_t)N * 12);
        int*      counts  = (int*)(p + (size_t)E * 8 + (size_t)N * 14);
        int*      offsets = counts + KMAX;        // K+1 slots
        int*      bhist   = (int*)inv2;           // alias: dead until phase1

        const int* srcA = eidx;
        const int* dstA = eidx + E;

        k_hist<<<SB, HT, 0, stream>>>(dstA, x, bhist, xpk, E, K, span, N);
        k_scanA<<<K, 64, 0, stream>>>(bhist, counts);
        k_scanB<<<1, KMAX, 0, stream>>>(counts, offsets, K);
        k_scatter<<<SB, SB_T, 0, stream>>>(srcA, dstA, attr, bhist, counts,
                                           offsets, ebuf, E, K, span);
        k_phase1<<<K, PT, 0, stream>>>(ebuf, offsets, xpk, x, a_x, tpk, inv2, N);
        k_phase2<<<K, PT, 0, stream>>>(ebuf, offsets, tpk, inv2, mask, out, N);
    } else {
        // proven R5 fallback (20N+64 bytes of ws)
        char* ws = (char*)d_ws;
        double2* pk      = (double2*)(ws);
        float*   acc2    = (float*)(ws + (size_t)16 * N);
        int*     tickets = (int*)(ws + (size_t)20 * N);

        hipMemsetAsync(d_ws, 0, (size_t)20 * N + 64, stream);

        const int sliceSz = (N + 7) / 8;
        const int nchunk  = (E + CHUNK - 1) / CHUNK;
        const int EGRID   = 2048;
        int ngrid = (N + BLK - 1) / BLK;
        const int NGRID   = ngrid < 2048 ? ngrid : 2048;

        edge_pass1<<<EGRID, BLK, 0, stream>>>(
            eidx, eidx + E, attr, x, pk, tickets, E, nchunk, sliceSz, N);
        node_mid<<<NGRID, BLK, 0, stream>>>(pk, a_x, N);
        edge_pass2<<<EGRID, BLK, 0, stream>>>(
            eidx, eidx + E, attr, (const float4*)pk, acc2, tickets,
            E, nchunk, sliceSz, N);
        node_out<<<NGRID, BLK, 0, stream>>>(acc2, mask, out, N);
    }
}